// Round 13
// baseline (334.899 us; speedup 1.0000x reference)
//
#include <hip/hip_runtime.h>
#include <hip/hip_bf16.h>

typedef __bf16 bf16;
typedef _Float16 f16;
typedef __bf16 v8bf __attribute__((ext_vector_type(8)));
typedef float v4f __attribute__((ext_vector_type(4)));

// ---------- constants ----------
#define DD 1024
#define LN_EPS 1e-5f

// output element offsets (all f32 in d_out)
#define O_Y     0
#define O_STATE 8192
#define O_IDXE  73728
#define O_RIDX  73792
#define O_WIDX  73824

// ws byte offsets (total 17404416 B — exact round-5/7 layout, proven in-bounds)
#define W_KV      0ull                      // bf16 [8][1032][1024] 16908288
#define W_STATE   16908288ull               // f32  [8][8][1024]      262144 (PoolA: state -> u -> s(f32))
#define W_LATL    17170432ull               // f32  [8][1024]          32768
#define W_QLN     17203200ull               // f32  [8][1024]  (c0[64] reuses after k_qp)
#define W_R2      17235968ull               // f32  [1024]
#define W_RSC     17240064ull               // f32  [64]
#define W_SSC     17240320ull               // f32  [64]
#define W_OATT    17240576ull               // PoolB 160KB: qp / lg(f16 132KB) / o_attn+lat1..lat2
#define W_LAT1    17273344ull
#define W_LNFFN   17306112ull
#define W_H1      17338880ull
#define W_LAT2    17371648ull

__device__ __forceinline__ float wred_sum(float v) {
#pragma unroll
  for (int o = 32; o; o >>= 1) v += __shfl_down(v, o, 64);
  return v;
}

__device__ __forceinline__ void top4_of8(const float* sc, int* ridx) {
  unsigned used = 0;
#pragma unroll
  for (int k = 0; k < 4; k++) {
    float best = -3.4e38f; int bi = 0;
    for (int s = 0; s < 8; s++)
      if (!((used >> s) & 1) && sc[s] > best) { best = sc[s]; bi = s; }
    used |= 1u << bi; ridx[k] = bi;
  }
}

// ---------- r2 = row norms of A_skew ----------
__global__ __launch_bounds__(256) void k_r2(const float* __restrict__ A, float* __restrict__ r2) {
  int row = blockIdx.x, t = threadIdx.x;
  const float* p = A + (size_t)row * DD;
  float s = 0.f;
  for (int j = t; j < DD; j += 256) { float x = p[j]; s += x * x; }
  s = wred_sum(s);
  __shared__ float sh[4];
  if ((t & 63) == 0) sh[t >> 6] = s;
  __syncthreads();
  if (t == 0) r2[row] = sh[0] + sh[1] + sh[2] + sh[3];
}

// ---------- read_scores + slot_scores ----------
__global__ __launch_bounds__(256) void k_scores(const float* __restrict__ state,
    const float* __restrict__ W_rg, const float* __restrict__ g_sl, const float* __restrict__ b_sl,
    const float* __restrict__ W_sl, float* __restrict__ rsc, float* __restrict__ ssc) {
  int row = blockIdx.x, t = threadIdx.x, l = t & 63, w = t >> 6;
  const float* p = state + (size_t)row * DD;
  float x[4]; float sum = 0.f, sq = 0.f, rs = 0.f;
#pragma unroll
  for (int i = 0; i < 4; i++) {
    int j = t + i * 256;
    x[i] = p[j];
    sum += x[i]; sq += x[i] * x[i];
    rs += x[i] * W_rg[j];
  }
  __shared__ float sh[3][4];
  sum = wred_sum(sum); sq = wred_sum(sq); rs = wred_sum(rs);
  if (l == 0) { sh[0][w] = sum; sh[1][w] = sq; sh[2][w] = rs; }
  __syncthreads();
  float m = (sh[0][0] + sh[0][1] + sh[0][2] + sh[0][3]) * (1.0f / 1024.0f);
  float var = (sh[1][0] + sh[1][1] + sh[1][2] + sh[1][3]) * (1.0f / 1024.0f) - m * m;
  float rsTot = sh[2][0] + sh[2][1] + sh[2][2] + sh[2][3];
  float inv = 1.0f / sqrtf(var + LN_EPS);
  __syncthreads();
  float ss = 0.f;
#pragma unroll
  for (int i = 0; i < 4; i++) {
    int j = t + i * 256;
    float ln = (x[i] - m) * inv * g_sl[j] + b_sl[j];
    ss += ln * W_sl[j];
  }
  ss = wred_sum(ss);
  if (l == 0) sh[0][w] = ss;
  __syncthreads();
  if (t == 0) { rsc[row] = rsTot; ssc[row] = sh[0][0] + sh[0][1] + sh[0][2] + sh[0][3]; }
}

// ---------- gate: LN_moe + gate logits + top2 -> idx_experts, read_idx (f32 out) ----------
__global__ __launch_bounds__(256) void k_gate(const float* __restrict__ state,
    const float* __restrict__ rsc, const float* __restrict__ g_moe, const float* __restrict__ b_moe,
    const float* __restrict__ Wg, float* __restrict__ out) {
  int b = blockIdx.x >> 2, k = blockIdx.x & 3;
  int t = threadIdx.x, l = t & 63, w = t >> 6;
  __shared__ float rs[8];
  __shared__ float red[2][4];
  __shared__ float gl[8];
  if (t < 8) rs[t] = rsc[b * 8 + t];
  __syncthreads();
  int ridx[4]; top4_of8(rs, ridx);
  int s = ridx[k];
  const float* p = state + (size_t)(b * 8 + s) * DD;
  float x[4]; float sum = 0.f, sq = 0.f;
#pragma unroll
  for (int i = 0; i < 4; i++) {
    int j = t + i * 256;
    x[i] = p[j]; sum += x[i]; sq += x[i] * x[i];
  }
  sum = wred_sum(sum); sq = wred_sum(sq);
  if (l == 0) { red[0][w] = sum; red[1][w] = sq; }
  __syncthreads();
  float m = (red[0][0] + red[0][1] + red[0][2] + red[0][3]) * (1.0f / 1024.0f);
  float var = (red[1][0] + red[1][1] + red[1][2] + red[1][3]) * (1.0f / 1024.0f) - m * m;
  float inv = 1.0f / sqrtf(var + LN_EPS);
  float lnv[4];
#pragma unroll
  for (int i = 0; i < 4; i++) {
    int j = t + i * 256;
    lnv[i] = (x[i] - m) * inv * g_moe[j] + b_moe[j];
  }
  __syncthreads();
  for (int e = 0; e < 8; e++) {
    float acc = 0.f;
#pragma unroll
    for (int i = 0; i < 4; i++) acc += lnv[i] * Wg[(size_t)e * DD + t + i * 256];
    acc = wred_sum(acc);
    if (l == 0) red[0][w] = acc;
    __syncthreads();
    if (t == 0) gl[e] = red[0][0] + red[0][1] + red[0][2] + red[0][3];
    __syncthreads();
  }
  if (t == 0) {
    int e0 = 0, e1 = 0; float b0 = -3.4e38f, b1 = -3.4e38f;
    for (int e = 0; e < 8; e++) {
      float v = gl[e];
      if (v > b0) { b1 = b0; e1 = e0; b0 = v; e0 = e; }
      else if (v > b1) { b1 = v; e1 = e; }
    }
    out[O_IDXE + (b * 4 + k) * 2 + 0] = (float)e0;
    out[O_IDXE + (b * 4 + k) * 2 + 1] = (float)e1;
    if (k == 0)
      for (int kk = 0; kk < 4; kk++) out[O_RIDX + b * 4 + kk] = (float)ridx[kk];
  }
}

// ---------- state update (f32 out) ----------
__global__ __launch_bounds__(256) void k_state(const float* __restrict__ state_in,
    const float* __restrict__ rsc, const float* __restrict__ ssc, const float* __restrict__ r2,
    float* __restrict__ state_ws, float* __restrict__ out) {
  int b = blockIdx.x, t = threadIdx.x;
  __shared__ float rs[8];
  if (t < 8) rs[t] = rsc[b * 8 + t];
  __syncthreads();
  int ridx[4]; top4_of8(rs, ridx);
  float lr[4];
#pragma unroll
  for (int k = 0; k < 4; k++) lr[k] = ssc[b * 8 + ridx[k]];
  int w0 = 0, w1 = 0; float b0 = -3.4e38f, b1 = -3.4e38f;
#pragma unroll
  for (int k = 0; k < 4; k++) {
    float v = lr[k];
    if (v > b0) { b1 = b0; w1 = w0; b0 = v; w0 = k; }
    else if (v > b1) { b1 = v; w1 = k; }
  }
  int wid0 = ridx[w0], wid1 = ridx[w1];
  float mx = fmaxf(lr[0], lr[1]);
  float e0 = expf(lr[0] - mx), e1 = expf(lr[1] - mx);
  float den = e0 + e1;
  float ws0 = e0 / den, ws1 = e1 / den;
  float resid = 1.0f - (ws0 + ws1);
#pragma unroll
  for (int i = 0; i < 4; i++) {
    int j = t + i * 256;
    float q = 1.0f - 0.03125f * r2[j];  // diag Cayley, c=0.125, O(c^4) dropped
    float lca = 0.f;
#pragma unroll
    for (int k = 0; k < 4; k++)
      lca += tanhf(state_in[(size_t)(b * 8 + ridx[k]) * DD + j] * q);
    float tj = tanhf(lca * 0.25f);
#pragma unroll
    for (int s = 0; s < 8; s++) {
      float a = (s == wid0) ? ws0 : ((s == wid1) ? ws1 : 0.0f);
      float v = a * tj + resid * state_in[(size_t)(b * 8 + s) * DD + j];
      state_ws[(size_t)(b * 8 + s) * DD + j] = v;
      out[O_STATE + (size_t)(b * 8 + s) * DD + j] = v;
    }
  }
  if (t == 0) {
    out[O_WIDX + b * 2 + 0] = (float)wid0;
    out[O_WIDX + b * 2 + 1] = (float)wid1;
  }
}

// ---------- MFMA BT GEMM — round-9 exact (plateau established; do not touch) ----------
#define MF(CC, AF, BF) CC = __builtin_amdgcn_mfma_f32_16x16x32_bf16(AF, BF, CC, 0, 0, 0)

__device__ __forceinline__ v4f gload4(const float* p) {
  v4f r;
  asm volatile("global_load_dwordx4 %0, %1, off" : "=v"(r) : "v"(p));
  return r;
}

__global__ __launch_bounds__(512, 4) void k_gemm(const float* __restrict__ A,
    const float* __restrict__ Bm, const float* __restrict__ bias, bf16* __restrict__ kvbuf,
    float* __restrict__ lat_last) {
  __shared__ bf16 smem[4][128 * 32];   // [0]=A-buf0 [1]=A-buf1 [2]=B-buf0 [3]=B-buf1
  const int t = threadIdx.x, l = t & 63, w = t >> 6;   // w: 0..7
  const int lin = blockIdx.y * 8 + blockIdx.x;
  const int mb = ((lin & 7) << 3) | ((lin >> 3) & 7);  // 8 A-band blocks per XCD
  const int nb = lin >> 6;
  const int mbase = mb * 128, nbase = nb * 128;
  const int wm = (w >> 1) * 32, wn = (w & 1) * 64;     // wave tile 32x64
  const int lm = l & 15, lk4 = l >> 4;

  v4f c00 = (v4f){0.f,0.f,0.f,0.f}, c01 = (v4f){0.f,0.f,0.f,0.f},
      c02 = (v4f){0.f,0.f,0.f,0.f}, c03 = (v4f){0.f,0.f,0.f,0.f},
      c10 = (v4f){0.f,0.f,0.f,0.f}, c11 = (v4f){0.f,0.f,0.f,0.f},
      c12 = (v4f){0.f,0.f,0.f,0.f}, c13 = (v4f){0.f,0.f,0.f,0.f};

  const int srow = t >> 2;          // 0..127 (one LDS row per thread)
  const int sch = t & 3;            // k-chunk of 8
  const int swA = srow * 32 + (sch ^ ((srow >> 1) & 3)) * 8;
  const int fa_base = (wm + lm) * 32 + ((lk4 ^ ((lm >> 1) & 3)) * 8);
  const int fb_base = (wn + lm) * 32 + ((lk4 ^ ((lm >> 1) & 3)) * 8);

  const float* aRow = A + (size_t)(mbase + srow) * 1024 + sch * 8;
  const float* bRow = Bm + (size_t)(nbase + srow) * 1024 + sch * 8;

  // prologue: issue k-chunk 0 (in flight until first half1's vmcnt(4))
  v4f a0 = gload4(aRow), a1 = gload4(aRow + 4);
  v4f b0 = gload4(bRow), b1 = gload4(bRow + 4);
  v4f na0, na1, nb0, nb1;

#define STAGE_AND_MFMA(AV0, AV1, BV0, BV1, AB, BB) do { \
    v8bf pa, pb; \
    _Pragma("unroll") \
    for (int r = 0; r < 4; r++) { pa[r] = (bf16)AV0[r]; pa[4 + r] = (bf16)AV1[r]; } \
    _Pragma("unroll") \
    for (int r = 0; r < 4; r++) { pb[r] = (bf16)BV0[r]; pb[4 + r] = (bf16)BV1[r]; } \
    *(v8bf*)(AB + swA) = pa; \
    *(v8bf*)(BB + swA) = pb; \
    asm volatile("s_waitcnt lgkmcnt(0)" ::: "memory"); \
    __builtin_amdgcn_s_barrier(); \
    asm volatile("" ::: "memory"); \
    v8bf af0 = *(const v8bf*)(AB + fa_base); \
    v8bf af1 = *(const v8bf*)(AB + fa_base + 512); \
    v8bf bq0 = *(const v8bf*)(BB + fb_base); \
    v8bf bq1 = *(const v8bf*)(BB + fb_base + 512); \
    v8bf bq2 = *(const v8bf*)(BB + fb_base + 1024); \
    v8bf bq3 = *(const v8bf*)(BB + fb_base + 1536); \
    MF(c00, af0, bq0); MF(c01, af0, bq1); MF(c02, af0, bq2); MF(c03, af0, bq3); \
    MF(c10, af1, bq0); MF(c11, af1, bq1); MF(c12, af1, bq2); MF(c13, af1, bq3); \
  } while (0)

  for (int k0 = 0; k0 < 1024; k0 += 64) {
    // ---- half 1: consume a* (chunk k0), prefetch na* (chunk k0+32) ----
    {
      const int kn = k0 + 32;
      na0 = gload4(aRow + kn); na1 = gload4(aRow + kn + 4);
      nb0 = gload4(bRow + kn); nb1 = gload4(bRow + kn + 4);
      asm volatile("s_waitcnt vmcnt(4)" : "+v"(a0), "+v"(a1), "+v"(b0), "+v"(b1));
      STAGE_AND_MFMA(a0, a1, b0, b1, (&smem[0][0]), (&smem[2][0]));
    }
    // ---- half 2: consume na* (chunk k0+32), prefetch a* (chunk k0+64) ----
    {
      const int kn = (k0 + 64 < 1024) ? (k0 + 64) : k0;  // last: harmless reload
      a0 = gload4(aRow + kn); a1 = gload4(aRow + kn + 4);
      b0 = gload4(bRow + kn); b1 = gload4(bRow + kn + 4);
      asm volatile("s_waitcnt vmcnt(4)" : "+v"(na0), "+v"(na1), "+v"(nb0), "+v"(nb1));
      STAGE_AND_MFMA(na0, na1, nb0, nb1, (&smem[1][0]), (&smem[3][0]));
    }
  }
#undef STAGE_AND_MFMA
  // drain the 4 dangling prefetch loads WITH TIES (round-8 lesson: keeps dest regs
  // live past the drain so the allocator cannot hand them to epilogue values).
  asm volatile("s_waitcnt vmcnt(0)" : "+v"(a0), "+v"(a1), "+v"(b0), "+v"(b1));

  // ---- epilogue: full 128x128 bf16 tile in LDS (all 32KB), then coalesced flush ----
  bf16* ot = &smem[0][0];             // 16384 bf16 = [128][128]
  const int er = (l >> 4) * 4;
  __syncthreads();                    // all K-loop LDS reads done

#define EPI_ONE(ii, jj, CC) do { \
    _Pragma("unroll") \
    for (int r = 0; r < 4; r++) { \
      int lrow = wm + (ii) * 16 + er + r; \
      int lcol = wn + (jj) * 16 + lm; \
      int grow = mbase + lrow; \
      int col = nbase + lcol; \
      int tok = grow & 1023, bb = grow >> 10; \
      int i2 = col & 511; \
      float fdiv = exp2f((float)i2 * (3.0f / 512.0f)); \
      float aarg = (float)tok / fdiv; \
      float pe = (col < 512) ? sinf(aarg) : cosf(aarg); \
      float v = CC[r] + bias[col] + pe; \
      ot[lrow * 128 + lcol] = (bf16)v; \
      if (tok == 1023) lat_last[(size_t)bb * 1024 + col] = v; \
    } \
  } while (0)

  EPI_ONE(0, 0, c00); EPI_ONE(0, 1, c01); EPI_ONE(0, 2, c02); EPI_ONE(0, 3, c03);
  EPI_ONE(1, 0, c10); EPI_ONE(1, 1, c11); EPI_ONE(1, 2, c12); EPI_ONE(1, 3, c13);
#undef EPI_ONE
  __syncthreads();
  {
    int rr = t >> 2;                  // 0..127
    int cc = (t & 3) * 32;            // 0,32,64,96
    int grow = mbase + rr;
    int tok = grow & 1023, bb = grow >> 10;
    bf16* dst = kvbuf + ((size_t)bb * 1032 + tok) * 1024 + nbase + cc;
    v8bf d0 = *(const v8bf*)(ot + rr * 128 + cc);
    v8bf d1 = *(const v8bf*)(ot + rr * 128 + cc + 8);
    v8bf d2 = *(const v8bf*)(ot + rr * 128 + cc + 16);
    v8bf d3 = *(const v8bf*)(ot + rr * 128 + cc + 24);
    *(v8bf*)dst = d0;
    *(v8bf*)(dst + 8) = d1;
    *(v8bf*)(dst + 16) = d2;
    *(v8bf*)(dst + 24) = d3;
  }
}

// ---------- LN (in-place on kv token rows; state rows from f32; q row from f32 lat_last) ----------
__global__ __launch_bounds__(256) void k_ln(bf16* __restrict__ kvbuf,
    const float* __restrict__ state_ws, const float* __restrict__ gkv, const float* __restrict__ bkv,
    const float* __restrict__ gq, const float* __restrict__ bq,
    float* __restrict__ qln, const float* __restrict__ lat_last) {
  int r = blockIdx.x, t = threadIdx.x, l = t & 63, w = t >> 6;
  int b = r / 1032, p = r % 1032;
  bf16* row = kvbuf + ((size_t)b * 1032 + p) * DD;
  float x[4]; float sum = 0.f, sq = 0.f;
  if (p == 1023) {
    const float* src = lat_last + (size_t)b * DD;
#pragma unroll
    for (int i = 0; i < 4; i++) {
      int j = t + i * 256;
      x[i] = src[j]; sum += x[i]; sq += x[i] * x[i];
    }
  } else if (p < 1024) {
#pragma unroll
    for (int i = 0; i < 4; i++) {
      int j = t + i * 256;
      x[i] = (float)row[j]; sum += x[i]; sq += x[i] * x[i];
    }
  } else {
    const float* src = state_ws + ((size_t)b * 8 + (p - 1024)) * DD;
#pragma unroll
    for (int i = 0; i < 4; i++) {
      int j = t + i * 256;
      x[i] = src[j]; sum += x[i]; sq += x[i] * x[i];
    }
  }
  __shared__ float sh[2][4];
  sum = wred_sum(sum); sq = wred_sum(sq);
  if (l == 0) { sh[0][w] = sum; sh[1][w] = sq; }
  __syncthreads();
  float m = (sh[0][0] + sh[0][1] + sh[0][2] + sh[0][3]) * (1.0f / 1024.0f);
  float var = (sh[1][0] + sh[1][1] + sh[1][2] + sh[1][3]) * (1.0f / 1024.0f) - m * m;
  float inv = 1.0f / sqrtf(var + LN_EPS);
  if (p == 1023) {
#pragma unroll
    for (int i = 0; i < 4; i++) {
      int j = t + i * 256;
      qln[(size_t)b * DD + j] = (x[i] - m) * inv * gq[j] + bq[j];
    }
  }
#pragma unroll
  for (int i = 0; i < 4; i++) {
    int j = t + i * 256;
    row[j] = (bf16)((x[i] - m) * inv * gkv[j] + bkv[j]);
  }
}

// ---------- LN of one f32 row per block (ffn pre-LN) ----------
__global__ __launch_bounds__(256) void k_ln_row(const float* __restrict__ src,
    const float* __restrict__ g, const float* __restrict__ bb, float* __restrict__ dst) {
  int b = blockIdx.x, t = threadIdx.x, l = t & 63, w = t >> 6;
  const float* p = src + (size_t)b * DD;
  float x[4]; float sum = 0.f, sq = 0.f;
#pragma unroll
  for (int i = 0; i < 4; i++) {
    int j = t + i * 256;
    x[i] = p[j]; sum += x[i]; sq += x[i] * x[i];
  }
  __shared__ float sh[2][4];
  sum = wred_sum(sum); sq = wred_sum(sq);
  if (l == 0) { sh[0][w] = sum; sh[1][w] = sq; }
  __syncthreads();
  float m = (sh[0][0] + sh[0][1] + sh[0][2] + sh[0][3]) * (1.0f / 1024.0f);
  float var = (sh[1][0] + sh[1][1] + sh[1][2] + sh[1][3]) * (1.0f / 1024.0f) - m * m;
  float inv = 1.0f / sqrtf(var + LN_EPS);
#pragma unroll
  for (int i = 0; i < 4; i++) {
    int j = t + i * 256;
    dst[(size_t)b * DD + j] = (x[i] - m) * inv * g[j] + bb[j];
  }
}

// ---------- batched GEMV: one block per n, weight row read ONCE, all 8 batches ----------
// Old k_qp/k_ov/k_gemv: one wave per (b,n); the 8 b-blocks for the same n were 1024
// grid-slots apart -> different XCDs (private L2s) -> each 4MB weight matrix fetched
// up to 8x from HBM (~32MB, ~5us floor per kernel x6 kernels). Now: block = one n,
// 4 waves split K (chains of 4x64), x[8][1024] staged in LDS (32KB), 8 named accs
// per lane, wred + 128B LDS reduce. Weight traffic 32MB -> 4MB per kernel.
// HSEL=1: x row = xin[(b*8 + (n>>7))] (k_ov's per-head S rows; n>>7 block-uniform).
// MODE: 0 res+store, 1 gelu, 2 res+store, 3 plain (y), 4 plain (qp/o_attn).
template <int MODE, int HSEL>
__global__ __launch_bounds__(256) void k_gemv8(const float* __restrict__ xin,
    const float* __restrict__ W, const float* __restrict__ bias,
    const float* __restrict__ res, float* __restrict__ outf) {
  int n = blockIdx.x;
  int t = threadIdx.x, l = t & 63, w = t >> 6;
  __shared__ float xs[8][1024];      // 32KB
  __shared__ float red[4][8];
  const int h = HSEL ? (n >> 7) : 0;
#pragma unroll
  for (int i = 0; i < 8; i++) {
    int flat = (i * 256 + t) * 4;
    int b = flat >> 10, col = flat & 1023;
    const float* src = xin + (size_t)(HSEL ? (b * 8 + h) : b) * DD + col;
    *(v4f*)&xs[b][col] = *(const v4f*)src;
  }
  __syncthreads();
  const float* wr = W + (size_t)n * DD + w * 256;
  float a0 = 0.f, a1 = 0.f, a2 = 0.f, a3 = 0.f, a4 = 0.f, a5 = 0.f, a6 = 0.f, a7 = 0.f;
#pragma unroll
  for (int k0 = 0; k0 < 256; k0 += 64) {
    float wv = wr[k0 + l];
    int kk = w * 256 + k0 + l;
    a0 += xs[0][kk] * wv;
    a1 += xs[1][kk] * wv;
    a2 += xs[2][kk] * wv;
    a3 += xs[3][kk] * wv;
    a4 += xs[4][kk] * wv;
    a5 += xs[5][kk] * wv;
    a6 += xs[6][kk] * wv;
    a7 += xs[7][kk] * wv;
  }
  a0 = wred_sum(a0); a1 = wred_sum(a1); a2 = wred_sum(a2); a3 = wred_sum(a3);
  a4 = wred_sum(a4); a5 = wred_sum(a5); a6 = wred_sum(a6); a7 = wred_sum(a7);
  if (l == 0) {
    red[w][0] = a0; red[w][1] = a1; red[w][2] = a2; red[w][3] = a3;
    red[w][4] = a4; red[w][5] = a5; red[w][6] = a6; red[w][7] = a7;
  }
  __syncthreads();
  if (t < 8) {
    float v = red[0][t] + red[1][t] + red[2][t] + red[3][t] + bias[n];
    size_t idx = (size_t)t * 1024 + n;
    if (MODE == 0) outf[idx] = res[idx] + v;
    if (MODE == 1) outf[idx] = 0.5f * v * (1.0f + erff(v * 0.70710678118654752f));
    if (MODE == 2) outf[idx] = res[idx] + v;
    if (MODE == 3) outf[idx] = v;
    if (MODE == 4) outf[idx] = v;
  }
}

// ---------- u = q-heads @ Wk^T, 1024-thread (4x d-split); fuses c0 on kt==0 ----------
__global__ __launch_bounds__(1024) void k_u(const float* __restrict__ qp,
    const float* __restrict__ Wi, const float* __restrict__ bi,
    float* __restrict__ u, float* __restrict__ c0) {
  int h = blockIdx.x >> 4, kt = blockIdx.x & 15;
  int t = threadIdx.x;
  __shared__ float qs[8][128];
  __shared__ float red[4][4][2][64];   // [dc][bh][a0/a1][k-lane] 8KB
  {
    int b = t >> 7, d = t & 127;
    qs[b][d] = qp[b * 1024 + h * 128 + d];
  }
  __syncthreads();
  int kl = t & 63;
  int k = kt * 64 + kl;
  int bh = (t >> 6) & 3;
  int dc = t >> 8;                     // 0..3
  const float* wkb = Wi + (size_t)(1024 + h * 128 + dc * 32) * DD + k;
  float a0 = 0.f, a1 = 0.f;
#pragma unroll 8
  for (int d = 0; d < 32; d++) {
    float wv = wkb[(size_t)d * DD];
    a0 += qs[bh][dc * 32 + d] * wv;
    a1 += qs[bh + 4][dc * 32 + d] * wv;
  }
  red[dc][bh][0][kl] = a0;
  red[dc][bh][1][kl] = a1;
  __syncthreads();
  if (dc == 0) {
    float s0 = red[0][bh][0][kl] + red[1][bh][0][kl] + red[2][bh][0][kl] + red[3][bh][0][kl];
    float s1 = red[0][bh][1][kl] + red[1][bh][1][kl] + red[2][bh][1][kl] + red[3][bh][1][kl];
    u[(size_t)(bh * 8 + h) * DD + k] = s0;
    u[(size_t)((bh + 4) * 8 + h) * DD + k] = s1;
  }
  // fused c0 (only 8 blocks do this): c0[b*8+h] = dot128(qp[b,h-slice], bi[1024+h-slice])
  if (kt == 0 && t < 512) {
    int b = t >> 6;
    float a = qp[b * 1024 + h * 128 + kl] * bi[1024 + h * 128 + kl]
            + qp[b * 1024 + h * 128 + 64 + kl] * bi[1024 + h * 128 + 64 + kl];
    a = wred_sum(a);
    if (kl == 0) c0[b * 8 + h] = a;
  }
}

__global__ __launch_bounds__(256) void k_lg(const float* __restrict__ u,
    const bf16* __restrict__ kvbuf, const float* __restrict__ c0, f16* __restrict__ lg) {
  int b = blockIdx.x / 33, tile = blockIdx.x % 33;
  int p0 = tile * 32, t = threadIdx.x;
  __shared__ bf16 kvs[32 * 1032];
  __shared__ float us[8 * 1032];
  const bf16* kvb = kvbuf + (size_t)b * 1032 * DD;
#pragma unroll
  for (int i = 0; i < 16; i++) {
    int flat = (i * 256 + t) * 8;
    int row = flat >> 10, col = flat & 1023;
    int gp = p0 + row; if (gp > 1031) gp = 1031;
    *(v8bf*)(kvs + row * 1032 + col) = *(const v8bf*)(kvb + (size_t)gp * DD + col);
  }
#pragma unroll
  for (int i = 0; i < 8; i++) {
    int flat = (i * 256 + t) * 4;
    int row = flat >> 10, col = flat & 1023;
    *(v4f*)(us + row * 1032 + col) = *(const v4f*)(u + (size_t)(b * 8 + row) * DD + col);
  }
  __syncthreads();
  int pl = t >> 3, h = t & 7;
  if (p0 + pl < 1032) {
    float acc = 0.f;
#pragma unroll
    for (int k = 0; k < 1024; k += 8) {
      v8bf kv8 = *(const v8bf*)(kvs + pl * 1032 + k);
#pragma unroll
      for (int j = 0; j < 8; j++) acc += us[h * 1032 + k + j] * (float)kv8[j];
    }
    lg[(size_t)(b * 8 + h) * 1032 + p0 + pl] =
        (f16)((acc + c0[b * 8 + h]) * 0.08838834764831845f);
  }
}

// ---------- softmax; fuses zeroing of the f32 S buffer (s aliases u, dead after k_lg) ----------
__global__ __launch_bounds__(256) void k_sm(f16* __restrict__ lg, float* __restrict__ s) {
  int t = threadIdx.x, l = t & 63, w = t >> 6;
  // fused s-zero: 65536 floats / 64 blocks = 1024 each (v4f per thread)
  *(v4f*)(s + (size_t)blockIdx.x * 1024 + t * 4) = (v4f){0.f, 0.f, 0.f, 0.f};
  f16* p = lg + (size_t)blockIdx.x * 1032;
  float x[5];
  float mx = -3.4e38f;
#pragma unroll
  for (int i = 0; i < 5; i++) {
    int idx = t + i * 256;
    if (idx < 1032) { x[i] = (float)p[idx]; mx = fmaxf(mx, x[i]); }
  }
  __shared__ float sh[4];
#pragma unroll
  for (int o = 32; o; o >>= 1) mx = fmaxf(mx, __shfl_down(mx, o, 64));
  if (l == 0) sh[w] = mx;
  __syncthreads();
  mx = fmaxf(fmaxf(sh[0], sh[1]), fmaxf(sh[2], sh[3]));
  __syncthreads();
  float sum = 0.f;
#pragma unroll
  for (int i = 0; i < 5; i++) {
    int idx = t + i * 256;
    if (idx < 1032) { x[i] = expf(x[i] - mx); sum += x[i]; }
  }
  sum = wred_sum(sum);
  if (l == 0) sh[w] = sum;
  __syncthreads();
  float inv = 1.0f / (sh[0] + sh[1] + sh[2] + sh[3]);
#pragma unroll
  for (int i = 0; i < 5; i++) {
    int idx = t + i * 256;
    if (idx < 1032) p[idx] = (f16)(x[i] * inv);
  }
}

// ---------- S = P @ KV, p-split for latency hiding ----------
__global__ __launch_bounds__(256) void k_s(const f16* __restrict__ lg,
    const bf16* __restrict__ kvbuf, float* __restrict__ s) {
  int lin = blockIdx.x;              // 8b * 16kt * 8pc
  int b = lin >> 7, kt = (lin >> 3) & 15, pc = lin & 7;
  int t = threadIdx.x, l = t & 63, w = t >> 6;
  __shared__ f16 wl[8][132];         // 129 used
  __shared__ float red[4][8][64];    // 8KB
  for (int i = t; i < 8 * 129; i += 256) {
    int h = i / 129, pp = i % 129;
    wl[h][pp] = lg[(size_t)(b * 8 + h) * 1032 + pc * 129 + pp];
  }
  __syncthreads();
  int k = kt * 64 + l;
  const bf16* kvb = kvbuf + (size_t)b * 1032 * DD + k;
  float a0 = 0.f, a1 = 0.f, a2 = 0.f, a3 = 0.f, a4 = 0.f, a5 = 0.f, a6 = 0.f, a7 = 0.f;
#pragma unroll 4
  for (int pp = w; pp < 129; pp += 4) {
    int p = pc * 129 + pp;
    float kvv = (float)kvb[(size_t)p * DD];
    a0 += (float)wl[0][pp] * kvv;
    a1 += (float)wl[1][pp] * kvv;
    a2 += (float)wl[2][pp] * kvv;
    a3 += (float)wl[3][pp] * kvv;
    a4 += (float)wl[4][pp] * kvv;
    a5 += (float)wl[5][pp] * kvv;
    a6 += (float)wl[6][pp] * kvv;
    a7 += (float)wl[7][pp] * kvv;
  }
  red[w][0][l] = a0; red[w][1][l] = a1; red[w][2][l] = a2; red[w][3][l] = a3;
  red[w][4][l] = a4; red[w][5][l] = a5; red[w][6][l] = a6; red[w][7][l] = a7;
  __syncthreads();
  int hh = t >> 6;                   // 0..3, handles h=hh and h=hh+4
  float r0 = red[0][hh][l] + red[1][hh][l] + red[2][hh][l] + red[3][hh][l];
  float r1 = red[0][hh + 4][l] + red[1][hh + 4][l] + red[2][hh + 4][l] + red[3][hh + 4][l];
  atomicAdd(&s[(size_t)(b * 8 + hh) * DD + k], r0);
  atomicAdd(&s[(size_t)(b * 8 + hh + 4) * DD + k], r1);
}

extern "C" void kernel_launch(void* const* d_in, const int* in_sizes, int n_in,
                              void* d_out, int out_size, void* d_ws, size_t ws_size,
                              hipStream_t stream) {
  const float* x        = (const float*)d_in[0];
  const float* state_in = (const float*)d_in[1];
  const float* W_rg     = (const float*)d_in[2];
  const float* ln_moe_g = (const float*)d_in[3];
  const float* ln_moe_b = (const float*)d_in[4];
  const float* W_gate   = (const float*)d_in[5];
  const float* A_skew   = (const float*)d_in[6];
  const float* ln_sl_g  = (const float*)d_in[7];
  const float* ln_sl_b  = (const float*)d_in[8];
  const float* W_slot   = (const float*)d_in[9];
  const float* W_oe     = (const float*)d_in[10];
  const float* b_oe     = (const float*)d_in[11];
  const float* ln_q_g   = (const float*)d_in[12];
  const float* ln_q_b   = (const float*)d_in[13];
  const float* ln_kv_g  = (const float*)d_in[14];
  const float* ln_kv_b  = (const float*)d_in[15];
  const float* in_w     = (const float*)d_in[16];
  const float* in_b     = (const float*)d_in[17];
  const float* out_w    = (const float*)d_in[18];
  const float* out_b    = (const float*)d_in[19];
  const float* ln_f_g   = (const float*)d_in[20];
  const float* ln_f_b   = (const float*)d_in[21];
  const float* W_fc1    = (const float*)d_in[22];
  const float* b_fc1    = (const float*)d_in[23];
  const float* W_fc2    = (const float*)d_in[24];
  const float* b_fc2    = (const float*)d_in[25];
  const float* W_out    = (const float*)d_in[26];
  const float* b_out    = (const float*)d_in[27];

  char* ws = (char*)d_ws;
  bf16*  kvbuf    = (bf16*)(ws + W_KV);
  float* state_ws = (float*)(ws + W_STATE);
  float* u_buf    = (float*)(ws + W_STATE);
  float* s_f32    = (float*)(ws + W_STATE);   // aliases u (dead after k_lg)
  float* lat_last = (float*)(ws + W_LATL);
  float* qln      = (float*)(ws + W_QLN);
  float* c0       = (float*)(ws + W_QLN);     // qln dead after k_qp
  float* r2       = (float*)(ws + W_R2);
  float* rsc      = (float*)(ws + W_RSC);
  float* ssc      = (float*)(ws + W_SSC);
  float* qp       = (float*)(ws + W_OATT);
  f16*   lg       = (f16*)(ws + W_OATT);
  float* o_attn   = (float*)(ws + W_OATT);
  float* lat1     = (float*)(ws + W_LAT1);
  float* lnffn    = (float*)(ws + W_LNFFN);
  float* h1       = (float*)(ws + W_H1);
  float* lat2     = (float*)(ws + W_LAT2);
  float* out = (float*)d_out;

  k_r2<<<1024, 256, 0, stream>>>(A_skew, r2);
  k_scores<<<64, 256, 0, stream>>>(state_in, W_rg, ln_sl_g, ln_sl_b, W_slot, rsc, ssc);
  k_gate<<<32, 256, 0, stream>>>(state_in, rsc, ln_moe_g, ln_moe_b, W_gate, out);
  k_state<<<8, 256, 0, stream>>>(state_in, rsc, ssc, r2, state_ws, out);
  k_gemm<<<dim3(8, 64), 512, 0, stream>>>(x, W_oe, b_oe, kvbuf, lat_last);
  k_ln<<<8256, 256, 0, stream>>>(kvbuf, state_ws, ln_kv_g, ln_kv_b, ln_q_g, ln_q_b, qln, lat_last);
  k_gemv8<4, 0><<<1024, 256, 0, stream>>>(qln, in_w, in_b, nullptr, qp);
  k_u<<<128, 1024, 0, stream>>>(qp, in_w, in_b, u_buf, c0);
  k_lg<<<264, 256, 0, stream>>>(u_buf, kvbuf, c0, lg);
  k_sm<<<64, 256, 0, stream>>>(lg, s_f32);
  k_s<<<1024, 256, 0, stream>>>(lg, kvbuf, s_f32);
  k_gemv8<4, 1><<<1024, 256, 0, stream>>>(s_f32, in_w + (size_t)2048 * DD, in_b + 2048,
                                          nullptr, o_attn);
  k_gemv8<0, 0><<<1024, 256, 0, stream>>>(o_attn, out_w, out_b, lat_last, lat1);
  k_ln_row<<<8, 256, 0, stream>>>(lat1, ln_f_g, ln_f_b, lnffn);
  k_gemv8<1, 0><<<1024, 256, 0, stream>>>(lnffn, W_fc1, b_fc1, nullptr, h1);
  k_gemv8<2, 0><<<1024, 256, 0, stream>>>(h1, W_fc2, b_fc2, lat1, lat2);
  k_gemv8<3, 0><<<1024, 256, 0, stream>>>(lat2, W_out, b_out, nullptr, out);
}

// Round 14
// 298.916 us; speedup vs baseline: 1.1204x; 1.1204x over previous
//
#include <hip/hip_runtime.h>
#include <hip/hip_bf16.h>

typedef __bf16 bf16;
typedef _Float16 f16;
typedef __bf16 v8bf __attribute__((ext_vector_type(8)));
typedef float v4f __attribute__((ext_vector_type(4)));

// ---------- constants ----------
#define DD 1024
#define LN_EPS 1e-5f

// output element offsets (all f32 in d_out)
#define O_Y     0
#define O_STATE 8192
#define O_IDXE  73728
#define O_RIDX  73792
#define O_WIDX  73824

// ws byte offsets (total 17404416 B — exact round-5/7 layout, proven in-bounds)
#define W_KV      0ull                      // bf16 [8][1032][1024] 16908288
#define W_STATE   16908288ull               // f32  [8][8][1024]      262144 (PoolA: state -> u -> s(f32))
#define W_LATL    17170432ull               // f32  [8][1024]          32768
#define W_QLN     17203200ull               // f32  [8][1024]  (c0[64] reuses after k_qp)
#define W_R2      17235968ull               // f32  [1024]
#define W_RSC     17240064ull               // f32  [64]
#define W_SSC     17240320ull               // f32  [64]
#define W_OATT    17240576ull               // PoolB 160KB: qp / lg(f16 132KB) / o_attn+lat1..lat2
#define W_LAT1    17273344ull
#define W_LNFFN   17306112ull
#define W_H1      17338880ull
#define W_LAT2    17371648ull

__device__ __forceinline__ float wred_sum(float v) {
#pragma unroll
  for (int o = 32; o; o >>= 1) v += __shfl_down(v, o, 64);
  return v;
}

__device__ __forceinline__ void top4_of8(const float* sc, int* ridx) {
  unsigned used = 0;
#pragma unroll
  for (int k = 0; k < 4; k++) {
    float best = -3.4e38f; int bi = 0;
    for (int s = 0; s < 8; s++)
      if (!((used >> s) & 1) && sc[s] > best) { best = sc[s]; bi = s; }
    used |= 1u << bi; ridx[k] = bi;
  }
}

// ---------- r2 = row norms of A_skew ----------
__global__ __launch_bounds__(256) void k_r2(const float* __restrict__ A, float* __restrict__ r2) {
  int row = blockIdx.x, t = threadIdx.x;
  const float* p = A + (size_t)row * DD;
  float s = 0.f;
  for (int j = t; j < DD; j += 256) { float x = p[j]; s += x * x; }
  s = wred_sum(s);
  __shared__ float sh[4];
  if ((t & 63) == 0) sh[t >> 6] = s;
  __syncthreads();
  if (t == 0) r2[row] = sh[0] + sh[1] + sh[2] + sh[3];
}

// ---------- read_scores + slot_scores ----------
__global__ __launch_bounds__(256) void k_scores(const float* __restrict__ state,
    const float* __restrict__ W_rg, const float* __restrict__ g_sl, const float* __restrict__ b_sl,
    const float* __restrict__ W_sl, float* __restrict__ rsc, float* __restrict__ ssc) {
  int row = blockIdx.x, t = threadIdx.x, l = t & 63, w = t >> 6;
  const float* p = state + (size_t)row * DD;
  float x[4]; float sum = 0.f, sq = 0.f, rs = 0.f;
#pragma unroll
  for (int i = 0; i < 4; i++) {
    int j = t + i * 256;
    x[i] = p[j];
    sum += x[i]; sq += x[i] * x[i];
    rs += x[i] * W_rg[j];
  }
  __shared__ float sh[3][4];
  sum = wred_sum(sum); sq = wred_sum(sq); rs = wred_sum(rs);
  if (l == 0) { sh[0][w] = sum; sh[1][w] = sq; sh[2][w] = rs; }
  __syncthreads();
  float m = (sh[0][0] + sh[0][1] + sh[0][2] + sh[0][3]) * (1.0f / 1024.0f);
  float var = (sh[1][0] + sh[1][1] + sh[1][2] + sh[1][3]) * (1.0f / 1024.0f) - m * m;
  float rsTot = sh[2][0] + sh[2][1] + sh[2][2] + sh[2][3];
  float inv = 1.0f / sqrtf(var + LN_EPS);
  __syncthreads();
  float ss = 0.f;
#pragma unroll
  for (int i = 0; i < 4; i++) {
    int j = t + i * 256;
    float ln = (x[i] - m) * inv * g_sl[j] + b_sl[j];
    ss += ln * W_sl[j];
  }
  ss = wred_sum(ss);
  if (l == 0) sh[0][w] = ss;
  __syncthreads();
  if (t == 0) { rsc[row] = rsTot; ssc[row] = sh[0][0] + sh[0][1] + sh[0][2] + sh[0][3]; }
}

// ---------- gate: LN_moe + gate logits + top2 -> idx_experts, read_idx (f32 out) ----------
__global__ __launch_bounds__(256) void k_gate(const float* __restrict__ state,
    const float* __restrict__ rsc, const float* __restrict__ g_moe, const float* __restrict__ b_moe,
    const float* __restrict__ Wg, float* __restrict__ out) {
  int b = blockIdx.x >> 2, k = blockIdx.x & 3;
  int t = threadIdx.x, l = t & 63, w = t >> 6;
  __shared__ float rs[8];
  __shared__ float red[2][4];
  __shared__ float gl[8];
  if (t < 8) rs[t] = rsc[b * 8 + t];
  __syncthreads();
  int ridx[4]; top4_of8(rs, ridx);
  int s = ridx[k];
  const float* p = state + (size_t)(b * 8 + s) * DD;
  float x[4]; float sum = 0.f, sq = 0.f;
#pragma unroll
  for (int i = 0; i < 4; i++) {
    int j = t + i * 256;
    x[i] = p[j]; sum += x[i]; sq += x[i] * x[i];
  }
  sum = wred_sum(sum); sq = wred_sum(sq);
  if (l == 0) { red[0][w] = sum; red[1][w] = sq; }
  __syncthreads();
  float m = (red[0][0] + red[0][1] + red[0][2] + red[0][3]) * (1.0f / 1024.0f);
  float var = (red[1][0] + red[1][1] + red[1][2] + red[1][3]) * (1.0f / 1024.0f) - m * m;
  float inv = 1.0f / sqrtf(var + LN_EPS);
  float lnv[4];
#pragma unroll
  for (int i = 0; i < 4; i++) {
    int j = t + i * 256;
    lnv[i] = (x[i] - m) * inv * g_moe[j] + b_moe[j];
  }
  __syncthreads();
  for (int e = 0; e < 8; e++) {
    float acc = 0.f;
#pragma unroll
    for (int i = 0; i < 4; i++) acc += lnv[i] * Wg[(size_t)e * DD + t + i * 256];
    acc = wred_sum(acc);
    if (l == 0) red[0][w] = acc;
    __syncthreads();
    if (t == 0) gl[e] = red[0][0] + red[0][1] + red[0][2] + red[0][3];
    __syncthreads();
  }
  if (t == 0) {
    int e0 = 0, e1 = 0; float b0 = -3.4e38f, b1 = -3.4e38f;
    for (int e = 0; e < 8; e++) {
      float v = gl[e];
      if (v > b0) { b1 = b0; e1 = e0; b0 = v; e0 = e; }
      else if (v > b1) { b1 = v; e1 = e; }
    }
    out[O_IDXE + (b * 4 + k) * 2 + 0] = (float)e0;
    out[O_IDXE + (b * 4 + k) * 2 + 1] = (float)e1;
    if (k == 0)
      for (int kk = 0; kk < 4; kk++) out[O_RIDX + b * 4 + kk] = (float)ridx[kk];
  }
}

// ---------- state update (f32 out) ----------
__global__ __launch_bounds__(256) void k_state(const float* __restrict__ state_in,
    const float* __restrict__ rsc, const float* __restrict__ ssc, const float* __restrict__ r2,
    float* __restrict__ state_ws, float* __restrict__ out) {
  int b = blockIdx.x, t = threadIdx.x;
  __shared__ float rs[8];
  if (t < 8) rs[t] = rsc[b * 8 + t];
  __syncthreads();
  int ridx[4]; top4_of8(rs, ridx);
  float lr[4];
#pragma unroll
  for (int k = 0; k < 4; k++) lr[k] = ssc[b * 8 + ridx[k]];
  int w0 = 0, w1 = 0; float b0 = -3.4e38f, b1 = -3.4e38f;
#pragma unroll
  for (int k = 0; k < 4; k++) {
    float v = lr[k];
    if (v > b0) { b1 = b0; w1 = w0; b0 = v; w0 = k; }
    else if (v > b1) { b1 = v; w1 = k; }
  }
  int wid0 = ridx[w0], wid1 = ridx[w1];
  float mx = fmaxf(lr[0], lr[1]);
  float e0 = expf(lr[0] - mx), e1 = expf(lr[1] - mx);
  float den = e0 + e1;
  float ws0 = e0 / den, ws1 = e1 / den;
  float resid = 1.0f - (ws0 + ws1);
#pragma unroll
  for (int i = 0; i < 4; i++) {
    int j = t + i * 256;
    float q = 1.0f - 0.03125f * r2[j];  // diag Cayley, c=0.125, O(c^4) dropped
    float lca = 0.f;
#pragma unroll
    for (int k = 0; k < 4; k++)
      lca += tanhf(state_in[(size_t)(b * 8 + ridx[k]) * DD + j] * q);
    float tj = tanhf(lca * 0.25f);
#pragma unroll
    for (int s = 0; s < 8; s++) {
      float a = (s == wid0) ? ws0 : ((s == wid1) ? ws1 : 0.0f);
      float v = a * tj + resid * state_in[(size_t)(b * 8 + s) * DD + j];
      state_ws[(size_t)(b * 8 + s) * DD + j] = v;
      out[O_STATE + (size_t)(b * 8 + s) * DD + j] = v;
    }
  }
  if (t == 0) {
    out[O_WIDX + b * 2 + 0] = (float)wid0;
    out[O_WIDX + b * 2 + 1] = (float)wid1;
  }
}

// ---------- MFMA BT GEMM — round-9 exact (plateau established; do not touch) ----------
#define MF(CC, AF, BF) CC = __builtin_amdgcn_mfma_f32_16x16x32_bf16(AF, BF, CC, 0, 0, 0)

__device__ __forceinline__ v4f gload4(const float* p) {
  v4f r;
  asm volatile("global_load_dwordx4 %0, %1, off" : "=v"(r) : "v"(p));
  return r;
}

__global__ __launch_bounds__(512, 4) void k_gemm(const float* __restrict__ A,
    const float* __restrict__ Bm, const float* __restrict__ bias, bf16* __restrict__ kvbuf,
    float* __restrict__ lat_last) {
  __shared__ bf16 smem[4][128 * 32];   // [0]=A-buf0 [1]=A-buf1 [2]=B-buf0 [3]=B-buf1
  const int t = threadIdx.x, l = t & 63, w = t >> 6;   // w: 0..7
  const int lin = blockIdx.y * 8 + blockIdx.x;
  const int mb = ((lin & 7) << 3) | ((lin >> 3) & 7);  // 8 A-band blocks per XCD
  const int nb = lin >> 6;
  const int mbase = mb * 128, nbase = nb * 128;
  const int wm = (w >> 1) * 32, wn = (w & 1) * 64;     // wave tile 32x64
  const int lm = l & 15, lk4 = l >> 4;

  v4f c00 = (v4f){0.f,0.f,0.f,0.f}, c01 = (v4f){0.f,0.f,0.f,0.f},
      c02 = (v4f){0.f,0.f,0.f,0.f}, c03 = (v4f){0.f,0.f,0.f,0.f},
      c10 = (v4f){0.f,0.f,0.f,0.f}, c11 = (v4f){0.f,0.f,0.f,0.f},
      c12 = (v4f){0.f,0.f,0.f,0.f}, c13 = (v4f){0.f,0.f,0.f,0.f};

  const int srow = t >> 2;          // 0..127 (one LDS row per thread)
  const int sch = t & 3;            // k-chunk of 8
  const int swA = srow * 32 + (sch ^ ((srow >> 1) & 3)) * 8;
  const int fa_base = (wm + lm) * 32 + ((lk4 ^ ((lm >> 1) & 3)) * 8);
  const int fb_base = (wn + lm) * 32 + ((lk4 ^ ((lm >> 1) & 3)) * 8);

  const float* aRow = A + (size_t)(mbase + srow) * 1024 + sch * 8;
  const float* bRow = Bm + (size_t)(nbase + srow) * 1024 + sch * 8;

  // prologue: issue k-chunk 0 (in flight until first half1's vmcnt(4))
  v4f a0 = gload4(aRow), a1 = gload4(aRow + 4);
  v4f b0 = gload4(bRow), b1 = gload4(bRow + 4);
  v4f na0, na1, nb0, nb1;

#define STAGE_AND_MFMA(AV0, AV1, BV0, BV1, AB, BB) do { \
    v8bf pa, pb; \
    _Pragma("unroll") \
    for (int r = 0; r < 4; r++) { pa[r] = (bf16)AV0[r]; pa[4 + r] = (bf16)AV1[r]; } \
    _Pragma("unroll") \
    for (int r = 0; r < 4; r++) { pb[r] = (bf16)BV0[r]; pb[4 + r] = (bf16)BV1[r]; } \
    *(v8bf*)(AB + swA) = pa; \
    *(v8bf*)(BB + swA) = pb; \
    asm volatile("s_waitcnt lgkmcnt(0)" ::: "memory"); \
    __builtin_amdgcn_s_barrier(); \
    asm volatile("" ::: "memory"); \
    v8bf af0 = *(const v8bf*)(AB + fa_base); \
    v8bf af1 = *(const v8bf*)(AB + fa_base + 512); \
    v8bf bq0 = *(const v8bf*)(BB + fb_base); \
    v8bf bq1 = *(const v8bf*)(BB + fb_base + 512); \
    v8bf bq2 = *(const v8bf*)(BB + fb_base + 1024); \
    v8bf bq3 = *(const v8bf*)(BB + fb_base + 1536); \
    MF(c00, af0, bq0); MF(c01, af0, bq1); MF(c02, af0, bq2); MF(c03, af0, bq3); \
    MF(c10, af1, bq0); MF(c11, af1, bq1); MF(c12, af1, bq2); MF(c13, af1, bq3); \
  } while (0)

  for (int k0 = 0; k0 < 1024; k0 += 64) {
    // ---- half 1: consume a* (chunk k0), prefetch na* (chunk k0+32) ----
    {
      const int kn = k0 + 32;
      na0 = gload4(aRow + kn); na1 = gload4(aRow + kn + 4);
      nb0 = gload4(bRow + kn); nb1 = gload4(bRow + kn + 4);
      asm volatile("s_waitcnt vmcnt(4)" : "+v"(a0), "+v"(a1), "+v"(b0), "+v"(b1));
      STAGE_AND_MFMA(a0, a1, b0, b1, (&smem[0][0]), (&smem[2][0]));
    }
    // ---- half 2: consume na* (chunk k0+32), prefetch a* (chunk k0+64) ----
    {
      const int kn = (k0 + 64 < 1024) ? (k0 + 64) : k0;  // last: harmless reload
      a0 = gload4(aRow + kn); a1 = gload4(aRow + kn + 4);
      b0 = gload4(bRow + kn); b1 = gload4(bRow + kn + 4);
      asm volatile("s_waitcnt vmcnt(4)" : "+v"(na0), "+v"(na1), "+v"(nb0), "+v"(nb1));
      STAGE_AND_MFMA(na0, na1, nb0, nb1, (&smem[1][0]), (&smem[3][0]));
    }
  }
#undef STAGE_AND_MFMA
  // drain the 4 dangling prefetch loads WITH TIES (round-8 lesson: keeps dest regs
  // live past the drain so the allocator cannot hand them to epilogue values).
  asm volatile("s_waitcnt vmcnt(0)" : "+v"(a0), "+v"(a1), "+v"(b0), "+v"(b1));

  // ---- epilogue: full 128x128 bf16 tile in LDS (all 32KB), then coalesced flush ----
  bf16* ot = &smem[0][0];             // 16384 bf16 = [128][128]
  const int er = (l >> 4) * 4;
  __syncthreads();                    // all K-loop LDS reads done

#define EPI_ONE(ii, jj, CC) do { \
    _Pragma("unroll") \
    for (int r = 0; r < 4; r++) { \
      int lrow = wm + (ii) * 16 + er + r; \
      int lcol = wn + (jj) * 16 + lm; \
      int grow = mbase + lrow; \
      int col = nbase + lcol; \
      int tok = grow & 1023, bb = grow >> 10; \
      int i2 = col & 511; \
      float fdiv = exp2f((float)i2 * (3.0f / 512.0f)); \
      float aarg = (float)tok / fdiv; \
      float pe = (col < 512) ? sinf(aarg) : cosf(aarg); \
      float v = CC[r] + bias[col] + pe; \
      ot[lrow * 128 + lcol] = (bf16)v; \
      if (tok == 1023) lat_last[(size_t)bb * 1024 + col] = v; \
    } \
  } while (0)

  EPI_ONE(0, 0, c00); EPI_ONE(0, 1, c01); EPI_ONE(0, 2, c02); EPI_ONE(0, 3, c03);
  EPI_ONE(1, 0, c10); EPI_ONE(1, 1, c11); EPI_ONE(1, 2, c12); EPI_ONE(1, 3, c13);
#undef EPI_ONE
  __syncthreads();
  {
    int rr = t >> 2;                  // 0..127
    int cc = (t & 3) * 32;            // 0,32,64,96
    int grow = mbase + rr;
    int tok = grow & 1023, bb = grow >> 10;
    bf16* dst = kvbuf + ((size_t)bb * 1032 + tok) * 1024 + nbase + cc;
    v8bf d0 = *(const v8bf*)(ot + rr * 128 + cc);
    v8bf d1 = *(const v8bf*)(ot + rr * 128 + cc + 8);
    v8bf d2 = *(const v8bf*)(ot + rr * 128 + cc + 16);
    v8bf d3 = *(const v8bf*)(ot + rr * 128 + cc + 24);
    *(v8bf*)dst = d0;
    *(v8bf*)(dst + 8) = d1;
    *(v8bf*)(dst + 16) = d2;
    *(v8bf*)(dst + 24) = d3;
  }
}

// ---------- LN (in-place on kv token rows; state rows from f32; q row from f32 lat_last) ----------
__global__ __launch_bounds__(256) void k_ln(bf16* __restrict__ kvbuf,
    const float* __restrict__ state_ws, const float* __restrict__ gkv, const float* __restrict__ bkv,
    const float* __restrict__ gq, const float* __restrict__ bq,
    float* __restrict__ qln, const float* __restrict__ lat_last) {
  int r = blockIdx.x, t = threadIdx.x, l = t & 63, w = t >> 6;
  int b = r / 1032, p = r % 1032;
  bf16* row = kvbuf + ((size_t)b * 1032 + p) * DD;
  float x[4]; float sum = 0.f, sq = 0.f;
  if (p == 1023) {
    const float* src = lat_last + (size_t)b * DD;
#pragma unroll
    for (int i = 0; i < 4; i++) {
      int j = t + i * 256;
      x[i] = src[j]; sum += x[i]; sq += x[i] * x[i];
    }
  } else if (p < 1024) {
#pragma unroll
    for (int i = 0; i < 4; i++) {
      int j = t + i * 256;
      x[i] = (float)row[j]; sum += x[i]; sq += x[i] * x[i];
    }
  } else {
    const float* src = state_ws + ((size_t)b * 8 + (p - 1024)) * DD;
#pragma unroll
    for (int i = 0; i < 4; i++) {
      int j = t + i * 256;
      x[i] = src[j]; sum += x[i]; sq += x[i] * x[i];
    }
  }
  __shared__ float sh[2][4];
  sum = wred_sum(sum); sq = wred_sum(sq);
  if (l == 0) { sh[0][w] = sum; sh[1][w] = sq; }
  __syncthreads();
  float m = (sh[0][0] + sh[0][1] + sh[0][2] + sh[0][3]) * (1.0f / 1024.0f);
  float var = (sh[1][0] + sh[1][1] + sh[1][2] + sh[1][3]) * (1.0f / 1024.0f) - m * m;
  float inv = 1.0f / sqrtf(var + LN_EPS);
  if (p == 1023) {
#pragma unroll
    for (int i = 0; i < 4; i++) {
      int j = t + i * 256;
      qln[(size_t)b * DD + j] = (x[i] - m) * inv * gq[j] + bq[j];
    }
  }
#pragma unroll
  for (int i = 0; i < 4; i++) {
    int j = t + i * 256;
    row[j] = (bf16)((x[i] - m) * inv * gkv[j] + bkv[j]);
  }
}

// ---------- LN of one f32 row per block (ffn pre-LN) ----------
__global__ __launch_bounds__(256) void k_ln_row(const float* __restrict__ src,
    const float* __restrict__ g, const float* __restrict__ bb, float* __restrict__ dst) {
  int b = blockIdx.x, t = threadIdx.x, l = t & 63, w = t >> 6;
  const float* p = src + (size_t)b * DD;
  float x[4]; float sum = 0.f, sq = 0.f;
#pragma unroll
  for (int i = 0; i < 4; i++) {
    int j = t + i * 256;
    x[i] = p[j]; sum += x[i]; sq += x[i] * x[i];
  }
  __shared__ float sh[2][4];
  sum = wred_sum(sum); sq = wred_sum(sq);
  if (l == 0) { sh[0][w] = sum; sh[1][w] = sq; }
  __syncthreads();
  float m = (sh[0][0] + sh[0][1] + sh[0][2] + sh[0][3]) * (1.0f / 1024.0f);
  float var = (sh[1][0] + sh[1][1] + sh[1][2] + sh[1][3]) * (1.0f / 1024.0f) - m * m;
  float inv = 1.0f / sqrtf(var + LN_EPS);
#pragma unroll
  for (int i = 0; i < 4; i++) {
    int j = t + i * 256;
    dst[(size_t)b * DD + j] = (x[i] - m) * inv * g[j] + bb[j];
  }
}

// ---------- batched GEMV: one block per n, weight row read ONCE, all 8 batches ----------
// HSEL=1: x row = xin[(b*8 + (n>>7))] (k_ov's per-head S rows; n>>7 block-uniform).
// MODE: 0 res+store, 1 gelu, 2 res+store, 3 plain (y), 4 plain (qp/o_attn).
template <int MODE, int HSEL>
__global__ __launch_bounds__(256) void k_gemv8(const float* __restrict__ xin,
    const float* __restrict__ W, const float* __restrict__ bias,
    const float* __restrict__ res, float* __restrict__ outf) {
  int n = blockIdx.x;
  int t = threadIdx.x, l = t & 63, w = t >> 6;
  __shared__ float xs[8][1024];      // 32KB
  __shared__ float red[4][8];
  const int h = HSEL ? (n >> 7) : 0;
#pragma unroll
  for (int i = 0; i < 8; i++) {
    int flat = (i * 256 + t) * 4;
    int b = flat >> 10, col = flat & 1023;
    const float* src = xin + (size_t)(HSEL ? (b * 8 + h) : b) * DD + col;
    *(v4f*)&xs[b][col] = *(const v4f*)src;
  }
  __syncthreads();
  const float* wr = W + (size_t)n * DD + w * 256;
  float a0 = 0.f, a1 = 0.f, a2 = 0.f, a3 = 0.f, a4 = 0.f, a5 = 0.f, a6 = 0.f, a7 = 0.f;
#pragma unroll
  for (int k0 = 0; k0 < 256; k0 += 64) {
    float wv = wr[k0 + l];
    int kk = w * 256 + k0 + l;
    a0 += xs[0][kk] * wv;
    a1 += xs[1][kk] * wv;
    a2 += xs[2][kk] * wv;
    a3 += xs[3][kk] * wv;
    a4 += xs[4][kk] * wv;
    a5 += xs[5][kk] * wv;
    a6 += xs[6][kk] * wv;
    a7 += xs[7][kk] * wv;
  }
  a0 = wred_sum(a0); a1 = wred_sum(a1); a2 = wred_sum(a2); a3 = wred_sum(a3);
  a4 = wred_sum(a4); a5 = wred_sum(a5); a6 = wred_sum(a6); a7 = wred_sum(a7);
  if (l == 0) {
    red[w][0] = a0; red[w][1] = a1; red[w][2] = a2; red[w][3] = a3;
    red[w][4] = a4; red[w][5] = a5; red[w][6] = a6; red[w][7] = a7;
  }
  __syncthreads();
  if (t < 8) {
    float v = red[0][t] + red[1][t] + red[2][t] + red[3][t] + bias[n];
    size_t idx = (size_t)t * 1024 + n;
    if (MODE == 0) outf[idx] = res[idx] + v;
    if (MODE == 1) outf[idx] = 0.5f * v * (1.0f + erff(v * 0.70710678118654752f));
    if (MODE == 2) outf[idx] = res[idx] + v;
    if (MODE == 3) outf[idx] = v;
    if (MODE == 4) outf[idx] = v;
  }
}

// ---------- u = q-heads @ Wk^T, 1024-thread (4x d-split); fuses c0 on kt==0 ----------
__global__ __launch_bounds__(1024) void k_u(const float* __restrict__ qp,
    const float* __restrict__ Wi, const float* __restrict__ bi,
    float* __restrict__ u, float* __restrict__ c0) {
  int h = blockIdx.x >> 4, kt = blockIdx.x & 15;
  int t = threadIdx.x;
  __shared__ float qs[8][128];
  __shared__ float red[4][4][2][64];   // [dc][bh][a0/a1][k-lane] 8KB
  {
    int b = t >> 7, d = t & 127;
    qs[b][d] = qp[b * 1024 + h * 128 + d];
  }
  __syncthreads();
  int kl = t & 63;
  int k = kt * 64 + kl;
  int bh = (t >> 6) & 3;
  int dc = t >> 8;                     // 0..3
  const float* wkb = Wi + (size_t)(1024 + h * 128 + dc * 32) * DD + k;
  float a0 = 0.f, a1 = 0.f;
#pragma unroll 8
  for (int d = 0; d < 32; d++) {
    float wv = wkb[(size_t)d * DD];
    a0 += qs[bh][dc * 32 + d] * wv;
    a1 += qs[bh + 4][dc * 32 + d] * wv;
  }
  red[dc][bh][0][kl] = a0;
  red[dc][bh][1][kl] = a1;
  __syncthreads();
  if (dc == 0) {
    float s0 = red[0][bh][0][kl] + red[1][bh][0][kl] + red[2][bh][0][kl] + red[3][bh][0][kl];
    float s1 = red[0][bh][1][kl] + red[1][bh][1][kl] + red[2][bh][1][kl] + red[3][bh][1][kl];
    u[(size_t)(bh * 8 + h) * DD + k] = s0;
    u[(size_t)((bh + 4) * 8 + h) * DD + k] = s1;
  }
  // fused c0 (only 8 blocks do this): c0[b*8+h] = dot128(qp[b,h-slice], bi[1024+h-slice])
  if (kt == 0 && t < 512) {
    int b = t >> 6;
    float a = qp[b * 1024 + h * 128 + kl] * bi[1024 + h * 128 + kl]
            + qp[b * 1024 + h * 128 + 64 + kl] * bi[1024 + h * 128 + 64 + kl];
    a = wred_sum(a);
    if (kl == 0) c0[b * 8 + h] = a;
  }
}

__global__ __launch_bounds__(256) void k_lg(const float* __restrict__ u,
    const bf16* __restrict__ kvbuf, const float* __restrict__ c0, f16* __restrict__ lg) {
  int b = blockIdx.x / 33, tile = blockIdx.x % 33;
  int p0 = tile * 32, t = threadIdx.x;
  __shared__ bf16 kvs[32 * 1032];
  __shared__ float us[8 * 1032];
  const bf16* kvb = kvbuf + (size_t)b * 1032 * DD;
#pragma unroll
  for (int i = 0; i < 16; i++) {
    int flat = (i * 256 + t) * 8;
    int row = flat >> 10, col = flat & 1023;
    int gp = p0 + row; if (gp > 1031) gp = 1031;
    *(v8bf*)(kvs + row * 1032 + col) = *(const v8bf*)(kvb + (size_t)gp * DD + col);
  }
#pragma unroll
  for (int i = 0; i < 8; i++) {
    int flat = (i * 256 + t) * 4;
    int row = flat >> 10, col = flat & 1023;
    *(v4f*)(us + row * 1032 + col) = *(const v4f*)(u + (size_t)(b * 8 + row) * DD + col);
  }
  __syncthreads();
  int pl = t >> 3, h = t & 7;
  if (p0 + pl < 1032) {
    float acc = 0.f;
#pragma unroll
    for (int k = 0; k < 1024; k += 8) {
      v8bf kv8 = *(const v8bf*)(kvs + pl * 1032 + k);
#pragma unroll
      for (int j = 0; j < 8; j++) acc += us[h * 1032 + k + j] * (float)kv8[j];
    }
    lg[(size_t)(b * 8 + h) * 1032 + p0 + pl] =
        (f16)((acc + c0[b * 8 + h]) * 0.08838834764831845f);
  }
}

// ---------- softmax; fuses zeroing of the f32 S buffer (s aliases u, dead after k_lg) ----------
__global__ __launch_bounds__(256) void k_sm(f16* __restrict__ lg, float* __restrict__ s) {
  int t = threadIdx.x, l = t & 63, w = t >> 6;
  // fused s-zero: 65536 floats / 64 blocks = 1024 each (v4f per thread)
  *(v4f*)(s + (size_t)blockIdx.x * 1024 + t * 4) = (v4f){0.f, 0.f, 0.f, 0.f};
  f16* p = lg + (size_t)blockIdx.x * 1032;
  float x[5];
  float mx = -3.4e38f;
#pragma unroll
  for (int i = 0; i < 5; i++) {
    int idx = t + i * 256;
    if (idx < 1032) { x[i] = (float)p[idx]; mx = fmaxf(mx, x[i]); }
  }
  __shared__ float sh[4];
#pragma unroll
  for (int o = 32; o; o >>= 1) mx = fmaxf(mx, __shfl_down(mx, o, 64));
  if (l == 0) sh[w] = mx;
  __syncthreads();
  mx = fmaxf(fmaxf(sh[0], sh[1]), fmaxf(sh[2], sh[3]));
  __syncthreads();
  float sum = 0.f;
#pragma unroll
  for (int i = 0; i < 5; i++) {
    int idx = t + i * 256;
    if (idx < 1032) { x[i] = expf(x[i] - mx); sum += x[i]; }
  }
  sum = wred_sum(sum);
  if (l == 0) sh[w] = sum;
  __syncthreads();
  float inv = 1.0f / (sh[0] + sh[1] + sh[2] + sh[3]);
#pragma unroll
  for (int i = 0; i < 5; i++) {
    int idx = t + i * 256;
    if (idx < 1032) p[idx] = (f16)(x[i] * inv);
  }
}

// ---------- S = P @ KV, p-split for latency hiding ----------
__global__ __launch_bounds__(256) void k_s(const f16* __restrict__ lg,
    const bf16* __restrict__ kvbuf, float* __restrict__ s) {
  int lin = blockIdx.x;              // 8b * 16kt * 8pc
  int b = lin >> 7, kt = (lin >> 3) & 15, pc = lin & 7;
  int t = threadIdx.x, l = t & 63, w = t >> 6;
  __shared__ f16 wl[8][132];         // 129 used
  __shared__ float red[4][8][64];    // 8KB
  for (int i = t; i < 8 * 129; i += 256) {
    int h = i / 129, pp = i % 129;
    wl[h][pp] = lg[(size_t)(b * 8 + h) * 1032 + pc * 129 + pp];
  }
  __syncthreads();
  int k = kt * 64 + l;
  const bf16* kvb = kvbuf + (size_t)b * 1032 * DD + k;
  float a0 = 0.f, a1 = 0.f, a2 = 0.f, a3 = 0.f, a4 = 0.f, a5 = 0.f, a6 = 0.f, a7 = 0.f;
#pragma unroll 4
  for (int pp = w; pp < 129; pp += 4) {
    int p = pc * 129 + pp;
    float kvv = (float)kvb[(size_t)p * DD];
    a0 += (float)wl[0][pp] * kvv;
    a1 += (float)wl[1][pp] * kvv;
    a2 += (float)wl[2][pp] * kvv;
    a3 += (float)wl[3][pp] * kvv;
    a4 += (float)wl[4][pp] * kvv;
    a5 += (float)wl[5][pp] * kvv;
    a6 += (float)wl[6][pp] * kvv;
    a7 += (float)wl[7][pp] * kvv;
  }
  red[w][0][l] = a0; red[w][1][l] = a1; red[w][2][l] = a2; red[w][3][l] = a3;
  red[w][4][l] = a4; red[w][5][l] = a5; red[w][6][l] = a6; red[w][7][l] = a7;
  __syncthreads();
  int hh = t >> 6;                   // 0..3, handles h=hh and h=hh+4
  float r0 = red[0][hh][l] + red[1][hh][l] + red[2][hh][l] + red[3][hh][l];
  float r1 = red[0][hh + 4][l] + red[1][hh + 4][l] + red[2][hh + 4][l] + red[3][hh + 4][l];
  atomicAdd(&s[(size_t)(b * 8 + hh) * DD + k], r0);
  atomicAdd(&s[(size_t)(b * 8 + hh + 4) * DD + k], r1);
}

extern "C" void kernel_launch(void* const* d_in, const int* in_sizes, int n_in,
                              void* d_out, int out_size, void* d_ws, size_t ws_size,
                              hipStream_t stream) {
  const float* x        = (const float*)d_in[0];
  const float* state_in = (const float*)d_in[1];
  const float* W_rg     = (const float*)d_in[2];
  const float* ln_moe_g = (const float*)d_in[3];
  const float* ln_moe_b = (const float*)d_in[4];
  const float* W_gate   = (const float*)d_in[5];
  const float* A_skew   = (const float*)d_in[6];
  const float* ln_sl_g  = (const float*)d_in[7];
  const float* ln_sl_b  = (const float*)d_in[8];
  const float* W_slot   = (const float*)d_in[9];
  const float* W_oe     = (const float*)d_in[10];
  const float* b_oe     = (const float*)d_in[11];
  const float* ln_q_g   = (const float*)d_in[12];
  const float* ln_q_b   = (const float*)d_in[13];
  const float* ln_kv_g  = (const float*)d_in[14];
  const float* ln_kv_b  = (const float*)d_in[15];
  const float* in_w     = (const float*)d_in[16];
  const float* in_b     = (const float*)d_in[17];
  const float* out_w    = (const float*)d_in[18];
  const float* out_b    = (const float*)d_in[19];
  const float* ln_f_g   = (const float*)d_in[20];
  const float* ln_f_b   = (const float*)d_in[21];
  const float* W_fc1    = (const float*)d_in[22];
  const float* b_fc1    = (const float*)d_in[23];
  const float* W_fc2    = (const float*)d_in[24];
  const float* b_fc2    = (const float*)d_in[25];
  const float* W_out    = (const float*)d_in[26];
  const float* b_out    = (const float*)d_in[27];

  char* ws = (char*)d_ws;
  bf16*  kvbuf    = (bf16*)(ws + W_KV);
  float* state_ws = (float*)(ws + W_STATE);
  float* u_buf    = (float*)(ws + W_STATE);
  float* s_f32    = (float*)(ws + W_STATE);   // aliases u (dead after k_lg)
  float* lat_last = (float*)(ws + W_LATL);
  float* qln      = (float*)(ws + W_QLN);
  float* c0       = (float*)(ws + W_QLN);     // qln dead after k_qp
  float* r2       = (float*)(ws + W_R2);
  float* rsc      = (float*)(ws + W_RSC);
  float* ssc      = (float*)(ws + W_SSC);
  float* qp       = (float*)(ws + W_OATT);
  f16*   lg       = (f16*)(ws + W_OATT);
  float* o_attn   = (float*)(ws + W_OATT);
  float* lat1     = (float*)(ws + W_LAT1);
  float* lnffn    = (float*)(ws + W_LNFFN);
  float* h1       = (float*)(ws + W_H1);
  float* lat2     = (float*)(ws + W_LAT2);
  float* out = (float*)d_out;

  k_r2<<<1024, 256, 0, stream>>>(A_skew, r2);
  k_scores<<<64, 256, 0, stream>>>(state_in, W_rg, ln_sl_g, ln_sl_b, W_slot, rsc, ssc);
  k_gate<<<32, 256, 0, stream>>>(state_in, rsc, ln_moe_g, ln_moe_b, W_gate, out);
  k_state<<<8, 256, 0, stream>>>(state_in, rsc, ssc, r2, state_ws, out);
  k_gemm<<<dim3(8, 64), 512, 0, stream>>>(x, W_oe, b_oe, kvbuf, lat_last);
  k_ln<<<8256, 256, 0, stream>>>(kvbuf, state_ws, ln_kv_g, ln_kv_b, ln_q_g, ln_q_b, qln, lat_last);
  k_gemv8<4, 0><<<1024, 256, 0, stream>>>(qln, in_w, in_b, nullptr, qp);
  k_u<<<128, 1024, 0, stream>>>(qp, in_w, in_b, u_buf, c0);
  k_lg<<<264, 256, 0, stream>>>(u_buf, kvbuf, c0, lg);
  k_sm<<<64, 256, 0, stream>>>(lg, s_f32);
  k_s<<<1024, 256, 0, stream>>>(lg, kvbuf, s_f32);
  k_gemv8<4, 1><<<1024, 256, 0, stream>>>(s_f32, in_w + (size_t)2048 * DD, in_b + 2048,
                                          nullptr, o_attn);
  k_gemv8<0, 0><<<1024, 256, 0, stream>>>(o_attn, out_w, out_b, lat_last, lat1);
  k_ln_row<<<8, 256, 0, stream>>>(lat1, ln_f_g, ln_f_b, lnffn);
  k_gemv8<1, 0><<<1024, 256, 0, stream>>>(lnffn, W_fc1, b_fc1, nullptr, h1);
  k_gemv8<2, 0><<<1024, 256, 0, stream>>>(h1, W_fc2, b_fc2, lat1, lat2);
  k_gemv8<3, 0><<<1024, 256, 0, stream>>>(lat2, W_out, b_out, nullptr, out);
}

// Round 15
// 287.698 us; speedup vs baseline: 1.1641x; 1.0390x over previous
//
#include <hip/hip_runtime.h>
#include <hip/hip_bf16.h>

typedef __bf16 bf16;
typedef _Float16 f16;
typedef __bf16 v8bf __attribute__((ext_vector_type(8)));
typedef float v4f __attribute__((ext_vector_type(4)));

// ---------- constants ----------
#define DD 1024
#define LN_EPS 1e-5f

// output element offsets (all f32 in d_out)
#define O_Y     0
#define O_STATE 8192
#define O_IDXE  73728
#define O_RIDX  73792
#define O_WIDX  73824

// ws byte offsets (total 17404416 B — exact round-5/7 layout, proven in-bounds)
#define W_KV      0ull                      // bf16 [8][1032][1024] 16908288
#define W_STATE   16908288ull               // f32  [8][8][1024]      262144 (PoolA: state -> u -> s(f32))
#define W_LATL    17170432ull               // f32  [8][1024]          32768
#define W_QLN     17203200ull               // f32  [8][1024]  (c0[64] reuses after k_qp)
#define W_R2      17235968ull               // f32  [1024]
#define W_RSC     17240064ull               // f32  [64]
#define W_SSC     17240320ull               // f32  [64]
#define W_OATT    17240576ull               // PoolB 160KB: qp / lg(f16 132KB) / o_attn+lat1..lat2
#define W_LAT1    17273344ull
#define W_LNFFN   17306112ull
#define W_H1      17338880ull
#define W_LAT2    17371648ull

__device__ __forceinline__ float wred_sum(float v) {
#pragma unroll
  for (int o = 32; o; o >>= 1) v += __shfl_down(v, o, 64);
  return v;
}

__device__ __forceinline__ void top4_of8(const float* sc, int* ridx) {
  unsigned used = 0;
#pragma unroll
  for (int k = 0; k < 4; k++) {
    float best = -3.4e38f; int bi = 0;
    for (int s = 0; s < 8; s++)
      if (!((used >> s) & 1) && sc[s] > best) { best = sc[s]; bi = s; }
    used |= 1u << bi; ridx[k] = bi;
  }
}

// ---------- fused: r2 row norms (blocks 0..1023) + read/slot scores (blocks 1024..1087) ----------
// k_r2 and k_scores are mutually independent (A_skew vs state inputs); fusing saves
// one launch. Both parts keep their exact round-12 shapes.
__global__ __launch_bounds__(256) void k_rs(const float* __restrict__ A, float* __restrict__ r2,
    const float* __restrict__ state, const float* __restrict__ W_rg,
    const float* __restrict__ g_sl, const float* __restrict__ b_sl,
    const float* __restrict__ W_sl, float* __restrict__ rsc, float* __restrict__ ssc) {
  int t = threadIdx.x, l = t & 63, w = t >> 6;
  if (blockIdx.x < 1024) {
    int row = blockIdx.x;
    const float* p = A + (size_t)row * DD;
    float s = 0.f;
    for (int j = t; j < DD; j += 256) { float x = p[j]; s += x * x; }
    s = wred_sum(s);
    __shared__ float sh1[4];
    if (l == 0) sh1[w] = s;
    __syncthreads();
    if (t == 0) r2[row] = sh1[0] + sh1[1] + sh1[2] + sh1[3];
    return;
  }
  int row = blockIdx.x - 1024;
  const float* p = state + (size_t)row * DD;
  float x[4]; float sum = 0.f, sq = 0.f, rs = 0.f;
#pragma unroll
  for (int i = 0; i < 4; i++) {
    int j = t + i * 256;
    x[i] = p[j];
    sum += x[i]; sq += x[i] * x[i];
    rs += x[i] * W_rg[j];
  }
  __shared__ float sh[3][4];
  sum = wred_sum(sum); sq = wred_sum(sq); rs = wred_sum(rs);
  if (l == 0) { sh[0][w] = sum; sh[1][w] = sq; sh[2][w] = rs; }
  __syncthreads();
  float m = (sh[0][0] + sh[0][1] + sh[0][2] + sh[0][3]) * (1.0f / 1024.0f);
  float var = (sh[1][0] + sh[1][1] + sh[1][2] + sh[1][3]) * (1.0f / 1024.0f) - m * m;
  float rsTot = sh[2][0] + sh[2][1] + sh[2][2] + sh[2][3];
  float inv = 1.0f / sqrtf(var + LN_EPS);
  __syncthreads();
  float ss = 0.f;
#pragma unroll
  for (int i = 0; i < 4; i++) {
    int j = t + i * 256;
    float ln = (x[i] - m) * inv * g_sl[j] + b_sl[j];
    ss += ln * W_sl[j];
  }
  ss = wred_sum(ss);
  if (l == 0) sh[0][w] = ss;
  __syncthreads();
  if (t == 0) { rsc[row] = rsTot; ssc[row] = sh[0][0] + sh[0][1] + sh[0][2] + sh[0][3]; }
}

// ---------- gate: LN_moe + gate logits + top2 -> idx_experts, read_idx (f32 out) ----------
__global__ __launch_bounds__(256) void k_gate(const float* __restrict__ state,
    const float* __restrict__ rsc, const float* __restrict__ g_moe, const float* __restrict__ b_moe,
    const float* __restrict__ Wg, float* __restrict__ out) {
  int b = blockIdx.x >> 2, k = blockIdx.x & 3;
  int t = threadIdx.x, l = t & 63, w = t >> 6;
  __shared__ float rs[8];
  __shared__ float red[2][4];
  __shared__ float gl[8];
  if (t < 8) rs[t] = rsc[b * 8 + t];
  __syncthreads();
  int ridx[4]; top4_of8(rs, ridx);
  int s = ridx[k];
  const float* p = state + (size_t)(b * 8 + s) * DD;
  float x[4]; float sum = 0.f, sq = 0.f;
#pragma unroll
  for (int i = 0; i < 4; i++) {
    int j = t + i * 256;
    x[i] = p[j]; sum += x[i]; sq += x[i] * x[i];
  }
  sum = wred_sum(sum); sq = wred_sum(sq);
  if (l == 0) { red[0][w] = sum; red[1][w] = sq; }
  __syncthreads();
  float m = (red[0][0] + red[0][1] + red[0][2] + red[0][3]) * (1.0f / 1024.0f);
  float var = (red[1][0] + red[1][1] + red[1][2] + red[1][3]) * (1.0f / 1024.0f) - m * m;
  float inv = 1.0f / sqrtf(var + LN_EPS);
  float lnv[4];
#pragma unroll
  for (int i = 0; i < 4; i++) {
    int j = t + i * 256;
    lnv[i] = (x[i] - m) * inv * g_moe[j] + b_moe[j];
  }
  __syncthreads();
  for (int e = 0; e < 8; e++) {
    float acc = 0.f;
#pragma unroll
    for (int i = 0; i < 4; i++) acc += lnv[i] * Wg[(size_t)e * DD + t + i * 256];
    acc = wred_sum(acc);
    if (l == 0) red[0][w] = acc;
    __syncthreads();
    if (t == 0) gl[e] = red[0][0] + red[0][1] + red[0][2] + red[0][3];
    __syncthreads();
  }
  if (t == 0) {
    int e0 = 0, e1 = 0; float b0 = -3.4e38f, b1 = -3.4e38f;
    for (int e = 0; e < 8; e++) {
      float v = gl[e];
      if (v > b0) { b1 = b0; e1 = e0; b0 = v; e0 = e; }
      else if (v > b1) { b1 = v; e1 = e; }
    }
    out[O_IDXE + (b * 4 + k) * 2 + 0] = (float)e0;
    out[O_IDXE + (b * 4 + k) * 2 + 1] = (float)e1;
    if (k == 0)
      for (int kk = 0; kk < 4; kk++) out[O_RIDX + b * 4 + kk] = (float)ridx[kk];
  }
}

// ---------- state update (f32 out) ----------
__global__ __launch_bounds__(256) void k_state(const float* __restrict__ state_in,
    const float* __restrict__ rsc, const float* __restrict__ ssc, const float* __restrict__ r2,
    float* __restrict__ state_ws, float* __restrict__ out) {
  int b = blockIdx.x, t = threadIdx.x;
  __shared__ float rs[8];
  if (t < 8) rs[t] = rsc[b * 8 + t];
  __syncthreads();
  int ridx[4]; top4_of8(rs, ridx);
  float lr[4];
#pragma unroll
  for (int k = 0; k < 4; k++) lr[k] = ssc[b * 8 + ridx[k]];
  int w0 = 0, w1 = 0; float b0 = -3.4e38f, b1 = -3.4e38f;
#pragma unroll
  for (int k = 0; k < 4; k++) {
    float v = lr[k];
    if (v > b0) { b1 = b0; w1 = w0; b0 = v; w0 = k; }
    else if (v > b1) { b1 = v; w1 = k; }
  }
  int wid0 = ridx[w0], wid1 = ridx[w1];
  float mx = fmaxf(lr[0], lr[1]);
  float e0 = expf(lr[0] - mx), e1 = expf(lr[1] - mx);
  float den = e0 + e1;
  float ws0 = e0 / den, ws1 = e1 / den;
  float resid = 1.0f - (ws0 + ws1);
#pragma unroll
  for (int i = 0; i < 4; i++) {
    int j = t + i * 256;
    float q = 1.0f - 0.03125f * r2[j];  // diag Cayley, c=0.125, O(c^4) dropped
    float lca = 0.f;
#pragma unroll
    for (int k = 0; k < 4; k++)
      lca += tanhf(state_in[(size_t)(b * 8 + ridx[k]) * DD + j] * q);
    float tj = tanhf(lca * 0.25f);
#pragma unroll
    for (int s = 0; s < 8; s++) {
      float a = (s == wid0) ? ws0 : ((s == wid1) ? ws1 : 0.0f);
      float v = a * tj + resid * state_in[(size_t)(b * 8 + s) * DD + j];
      state_ws[(size_t)(b * 8 + s) * DD + j] = v;
      out[O_STATE + (size_t)(b * 8 + s) * DD + j] = v;
    }
  }
  if (t == 0) {
    out[O_WIDX + b * 2 + 0] = (float)wid0;
    out[O_WIDX + b * 2 + 1] = (float)wid1;
  }
}

// ---------- MFMA BT GEMM — round-9 exact (plateau established; do not touch) ----------
#define MF(CC, AF, BF) CC = __builtin_amdgcn_mfma_f32_16x16x32_bf16(AF, BF, CC, 0, 0, 0)

__device__ __forceinline__ v4f gload4(const float* p) {
  v4f r;
  asm volatile("global_load_dwordx4 %0, %1, off" : "=v"(r) : "v"(p));
  return r;
}

__global__ __launch_bounds__(512, 4) void k_gemm(const float* __restrict__ A,
    const float* __restrict__ Bm, const float* __restrict__ bias, bf16* __restrict__ kvbuf,
    float* __restrict__ lat_last) {
  __shared__ bf16 smem[4][128 * 32];   // [0]=A-buf0 [1]=A-buf1 [2]=B-buf0 [3]=B-buf1
  const int t = threadIdx.x, l = t & 63, w = t >> 6;   // w: 0..7
  const int lin = blockIdx.y * 8 + blockIdx.x;
  const int mb = ((lin & 7) << 3) | ((lin >> 3) & 7);  // 8 A-band blocks per XCD
  const int nb = lin >> 6;
  const int mbase = mb * 128, nbase = nb * 128;
  const int wm = (w >> 1) * 32, wn = (w & 1) * 64;     // wave tile 32x64
  const int lm = l & 15, lk4 = l >> 4;

  v4f c00 = (v4f){0.f,0.f,0.f,0.f}, c01 = (v4f){0.f,0.f,0.f,0.f},
      c02 = (v4f){0.f,0.f,0.f,0.f}, c03 = (v4f){0.f,0.f,0.f,0.f},
      c10 = (v4f){0.f,0.f,0.f,0.f}, c11 = (v4f){0.f,0.f,0.f,0.f},
      c12 = (v4f){0.f,0.f,0.f,0.f}, c13 = (v4f){0.f,0.f,0.f,0.f};

  const int srow = t >> 2;          // 0..127 (one LDS row per thread)
  const int sch = t & 3;            // k-chunk of 8
  const int swA = srow * 32 + (sch ^ ((srow >> 1) & 3)) * 8;
  const int fa_base = (wm + lm) * 32 + ((lk4 ^ ((lm >> 1) & 3)) * 8);
  const int fb_base = (wn + lm) * 32 + ((lk4 ^ ((lm >> 1) & 3)) * 8);

  const float* aRow = A + (size_t)(mbase + srow) * 1024 + sch * 8;
  const float* bRow = Bm + (size_t)(nbase + srow) * 1024 + sch * 8;

  // prologue: issue k-chunk 0 (in flight until first half1's vmcnt(4))
  v4f a0 = gload4(aRow), a1 = gload4(aRow + 4);
  v4f b0 = gload4(bRow), b1 = gload4(bRow + 4);
  v4f na0, na1, nb0, nb1;

#define STAGE_AND_MFMA(AV0, AV1, BV0, BV1, AB, BB) do { \
    v8bf pa, pb; \
    _Pragma("unroll") \
    for (int r = 0; r < 4; r++) { pa[r] = (bf16)AV0[r]; pa[4 + r] = (bf16)AV1[r]; } \
    _Pragma("unroll") \
    for (int r = 0; r < 4; r++) { pb[r] = (bf16)BV0[r]; pb[4 + r] = (bf16)BV1[r]; } \
    *(v8bf*)(AB + swA) = pa; \
    *(v8bf*)(BB + swA) = pb; \
    asm volatile("s_waitcnt lgkmcnt(0)" ::: "memory"); \
    __builtin_amdgcn_s_barrier(); \
    asm volatile("" ::: "memory"); \
    v8bf af0 = *(const v8bf*)(AB + fa_base); \
    v8bf af1 = *(const v8bf*)(AB + fa_base + 512); \
    v8bf bq0 = *(const v8bf*)(BB + fb_base); \
    v8bf bq1 = *(const v8bf*)(BB + fb_base + 512); \
    v8bf bq2 = *(const v8bf*)(BB + fb_base + 1024); \
    v8bf bq3 = *(const v8bf*)(BB + fb_base + 1536); \
    MF(c00, af0, bq0); MF(c01, af0, bq1); MF(c02, af0, bq2); MF(c03, af0, bq3); \
    MF(c10, af1, bq0); MF(c11, af1, bq1); MF(c12, af1, bq2); MF(c13, af1, bq3); \
  } while (0)

  for (int k0 = 0; k0 < 1024; k0 += 64) {
    // ---- half 1: consume a* (chunk k0), prefetch na* (chunk k0+32) ----
    {
      const int kn = k0 + 32;
      na0 = gload4(aRow + kn); na1 = gload4(aRow + kn + 4);
      nb0 = gload4(bRow + kn); nb1 = gload4(bRow + kn + 4);
      asm volatile("s_waitcnt vmcnt(4)" : "+v"(a0), "+v"(a1), "+v"(b0), "+v"(b1));
      STAGE_AND_MFMA(a0, a1, b0, b1, (&smem[0][0]), (&smem[2][0]));
    }
    // ---- half 2: consume na* (chunk k0+32), prefetch a* (chunk k0+64) ----
    {
      const int kn = (k0 + 64 < 1024) ? (k0 + 64) : k0;  // last: harmless reload
      a0 = gload4(aRow + kn); a1 = gload4(aRow + kn + 4);
      b0 = gload4(bRow + kn); b1 = gload4(bRow + kn + 4);
      asm volatile("s_waitcnt vmcnt(4)" : "+v"(na0), "+v"(na1), "+v"(nb0), "+v"(nb1));
      STAGE_AND_MFMA(na0, na1, nb0, nb1, (&smem[1][0]), (&smem[3][0]));
    }
  }
#undef STAGE_AND_MFMA
  // drain the 4 dangling prefetch loads WITH TIES (round-8 lesson: keeps dest regs
  // live past the drain so the allocator cannot hand them to epilogue values).
  asm volatile("s_waitcnt vmcnt(0)" : "+v"(a0), "+v"(a1), "+v"(b0), "+v"(b1));

  // ---- epilogue: full 128x128 bf16 tile in LDS (all 32KB), then coalesced flush ----
  bf16* ot = &smem[0][0];             // 16384 bf16 = [128][128]
  const int er = (l >> 4) * 4;
  __syncthreads();                    // all K-loop LDS reads done

#define EPI_ONE(ii, jj, CC) do { \
    _Pragma("unroll") \
    for (int r = 0; r < 4; r++) { \
      int lrow = wm + (ii) * 16 + er + r; \
      int lcol = wn + (jj) * 16 + lm; \
      int grow = mbase + lrow; \
      int col = nbase + lcol; \
      int tok = grow & 1023, bb = grow >> 10; \
      int i2 = col & 511; \
      float fdiv = exp2f((float)i2 * (3.0f / 512.0f)); \
      float aarg = (float)tok / fdiv; \
      float pe = (col < 512) ? sinf(aarg) : cosf(aarg); \
      float v = CC[r] + bias[col] + pe; \
      ot[lrow * 128 + lcol] = (bf16)v; \
      if (tok == 1023) lat_last[(size_t)bb * 1024 + col] = v; \
    } \
  } while (0)

  EPI_ONE(0, 0, c00); EPI_ONE(0, 1, c01); EPI_ONE(0, 2, c02); EPI_ONE(0, 3, c03);
  EPI_ONE(1, 0, c10); EPI_ONE(1, 1, c11); EPI_ONE(1, 2, c12); EPI_ONE(1, 3, c13);
#undef EPI_ONE
  __syncthreads();
  {
    int rr = t >> 2;                  // 0..127
    int cc = (t & 3) * 32;            // 0,32,64,96
    int grow = mbase + rr;
    int tok = grow & 1023, bb = grow >> 10;
    bf16* dst = kvbuf + ((size_t)bb * 1032 + tok) * 1024 + nbase + cc;
    v8bf d0 = *(const v8bf*)(ot + rr * 128 + cc);
    v8bf d1 = *(const v8bf*)(ot + rr * 128 + cc + 8);
    v8bf d2 = *(const v8bf*)(ot + rr * 128 + cc + 16);
    v8bf d3 = *(const v8bf*)(ot + rr * 128 + cc + 24);
    *(v8bf*)dst = d0;
    *(v8bf*)(dst + 8) = d1;
    *(v8bf*)(dst + 16) = d2;
    *(v8bf*)(dst + 24) = d3;
  }
}

// ---------- LN (in-place on kv token rows; state rows from f32; q row from f32 lat_last) ----------
__global__ __launch_bounds__(256) void k_ln(bf16* __restrict__ kvbuf,
    const float* __restrict__ state_ws, const float* __restrict__ gkv, const float* __restrict__ bkv,
    const float* __restrict__ gq, const float* __restrict__ bq,
    float* __restrict__ qln, const float* __restrict__ lat_last) {
  int r = blockIdx.x, t = threadIdx.x, l = t & 63, w = t >> 6;
  int b = r / 1032, p = r % 1032;
  bf16* row = kvbuf + ((size_t)b * 1032 + p) * DD;
  float x[4]; float sum = 0.f, sq = 0.f;
  if (p == 1023) {
    const float* src = lat_last + (size_t)b * DD;
#pragma unroll
    for (int i = 0; i < 4; i++) {
      int j = t + i * 256;
      x[i] = src[j]; sum += x[i]; sq += x[i] * x[i];
    }
  } else if (p < 1024) {
#pragma unroll
    for (int i = 0; i < 4; i++) {
      int j = t + i * 256;
      x[i] = (float)row[j]; sum += x[i]; sq += x[i] * x[i];
    }
  } else {
    const float* src = state_ws + ((size_t)b * 8 + (p - 1024)) * DD;
#pragma unroll
    for (int i = 0; i < 4; i++) {
      int j = t + i * 256;
      x[i] = src[j]; sum += x[i]; sq += x[i] * x[i];
    }
  }
  __shared__ float sh[2][4];
  sum = wred_sum(sum); sq = wred_sum(sq);
  if (l == 0) { sh[0][w] = sum; sh[1][w] = sq; }
  __syncthreads();
  float m = (sh[0][0] + sh[0][1] + sh[0][2] + sh[0][3]) * (1.0f / 1024.0f);
  float var = (sh[1][0] + sh[1][1] + sh[1][2] + sh[1][3]) * (1.0f / 1024.0f) - m * m;
  float inv = 1.0f / sqrtf(var + LN_EPS);
  if (p == 1023) {
#pragma unroll
    for (int i = 0; i < 4; i++) {
      int j = t + i * 256;
      qln[(size_t)b * DD + j] = (x[i] - m) * inv * gq[j] + bq[j];
    }
  }
#pragma unroll
  for (int i = 0; i < 4; i++) {
    int j = t + i * 256;
    row[j] = (bf16)((x[i] - m) * inv * gkv[j] + bkv[j]);
  }
}

// ---------- LN of one f32 row per block (ffn pre-LN) ----------
__global__ __launch_bounds__(256) void k_ln_row(const float* __restrict__ src,
    const float* __restrict__ g, const float* __restrict__ bb, float* __restrict__ dst) {
  int b = blockIdx.x, t = threadIdx.x, l = t & 63, w = t >> 6;
  const float* p = src + (size_t)b * DD;
  float x[4]; float sum = 0.f, sq = 0.f;
#pragma unroll
  for (int i = 0; i < 4; i++) {
    int j = t + i * 256;
    x[i] = p[j]; sum += x[i]; sq += x[i] * x[i];
  }
  __shared__ float sh[2][4];
  sum = wred_sum(sum); sq = wred_sum(sq);
  if (l == 0) { sh[0][w] = sum; sh[1][w] = sq; }
  __syncthreads();
  float m = (sh[0][0] + sh[0][1] + sh[0][2] + sh[0][3]) * (1.0f / 1024.0f);
  float var = (sh[1][0] + sh[1][1] + sh[1][2] + sh[1][3]) * (1.0f / 1024.0f) - m * m;
  float inv = 1.0f / sqrtf(var + LN_EPS);
#pragma unroll
  for (int i = 0; i < 4; i++) {
    int j = t + i * 256;
    dst[(size_t)b * DD + j] = (x[i] - m) * inv * g[j] + bb[j];
  }
}

// ---------- attention pipeline (round-12 per-wave GEMV forms — measured best) ----------
__global__ __launch_bounds__(256) void k_qp(const float* __restrict__ qln,
    const float* __restrict__ Wi, const float* __restrict__ bi, float* __restrict__ qp) {
  int idx = blockIdx.x * 4 + (threadIdx.x >> 6);
  int l = threadIdx.x & 63;
  int b = idx >> 10, n = idx & 1023;
  const float* xr = qln + (size_t)b * DD;
  const float* wr = Wi + (size_t)n * DD;
  float acc = 0.f;
#pragma unroll
  for (int k0 = 0; k0 < 1024; k0 += 64) acc += xr[k0 + l] * wr[k0 + l];
  acc = wred_sum(acc);
  if (l == 0) qp[idx] = acc + bi[n];
}

// ---------- u = q-heads @ Wk^T, 1024-thread (4x d-split); fuses c0 on kt==0 ----------
__global__ __launch_bounds__(1024) void k_u(const float* __restrict__ qp,
    const float* __restrict__ Wi, const float* __restrict__ bi,
    float* __restrict__ u, float* __restrict__ c0) {
  int h = blockIdx.x >> 4, kt = blockIdx.x & 15;
  int t = threadIdx.x;
  __shared__ float qs[8][128];
  __shared__ float red[4][4][2][64];   // [dc][bh][a0/a1][k-lane] 8KB
  {
    int b = t >> 7, d = t & 127;
    qs[b][d] = qp[b * 1024 + h * 128 + d];
  }
  __syncthreads();
  int kl = t & 63;
  int k = kt * 64 + kl;
  int bh = (t >> 6) & 3;
  int dc = t >> 8;                     // 0..3
  const float* wkb = Wi + (size_t)(1024 + h * 128 + dc * 32) * DD + k;
  float a0 = 0.f, a1 = 0.f;
#pragma unroll 8
  for (int d = 0; d < 32; d++) {
    float wv = wkb[(size_t)d * DD];
    a0 += qs[bh][dc * 32 + d] * wv;
    a1 += qs[bh + 4][dc * 32 + d] * wv;
  }
  red[dc][bh][0][kl] = a0;
  red[dc][bh][1][kl] = a1;
  __syncthreads();
  if (dc == 0) {
    float s0 = red[0][bh][0][kl] + red[1][bh][0][kl] + red[2][bh][0][kl] + red[3][bh][0][kl];
    float s1 = red[0][bh][1][kl] + red[1][bh][1][kl] + red[2][bh][1][kl] + red[3][bh][1][kl];
    u[(size_t)(bh * 8 + h) * DD + k] = s0;
    u[(size_t)((bh + 4) * 8 + h) * DD + k] = s1;
  }
  // fused c0 (only 8 blocks do this): c0[b*8+h] = dot128(qp[b,h-slice], bi[1024+h-slice])
  if (kt == 0 && t < 512) {
    int b = t >> 6;
    float a = qp[b * 1024 + h * 128 + kl] * bi[1024 + h * 128 + kl]
            + qp[b * 1024 + h * 128 + 64 + kl] * bi[1024 + h * 128 + 64 + kl];
    a = wred_sum(a);
    if (kl == 0) c0[b * 8 + h] = a;
  }
}

__global__ __launch_bounds__(256) void k_lg(const float* __restrict__ u,
    const bf16* __restrict__ kvbuf, const float* __restrict__ c0, f16* __restrict__ lg) {
  int b = blockIdx.x / 33, tile = blockIdx.x % 33;
  int p0 = tile * 32, t = threadIdx.x;
  __shared__ bf16 kvs[32 * 1032];
  __shared__ float us[8 * 1032];
  const bf16* kvb = kvbuf + (size_t)b * 1032 * DD;
#pragma unroll
  for (int i = 0; i < 16; i++) {
    int flat = (i * 256 + t) * 8;
    int row = flat >> 10, col = flat & 1023;
    int gp = p0 + row; if (gp > 1031) gp = 1031;
    *(v8bf*)(kvs + row * 1032 + col) = *(const v8bf*)(kvb + (size_t)gp * DD + col);
  }
#pragma unroll
  for (int i = 0; i < 8; i++) {
    int flat = (i * 256 + t) * 4;
    int row = flat >> 10, col = flat & 1023;
    *(v4f*)(us + row * 1032 + col) = *(const v4f*)(u + (size_t)(b * 8 + row) * DD + col);
  }
  __syncthreads();
  int pl = t >> 3, h = t & 7;
  if (p0 + pl < 1032) {
    float acc = 0.f;
#pragma unroll
    for (int k = 0; k < 1024; k += 8) {
      v8bf kv8 = *(const v8bf*)(kvs + pl * 1032 + k);
#pragma unroll
      for (int j = 0; j < 8; j++) acc += us[h * 1032 + k + j] * (float)kv8[j];
    }
    lg[(size_t)(b * 8 + h) * 1032 + p0 + pl] =
        (f16)((acc + c0[b * 8 + h]) * 0.08838834764831845f);
  }
}

// ---------- softmax; fuses zeroing of the f32 S buffer (s aliases u, dead after k_lg) ----------
__global__ __launch_bounds__(256) void k_sm(f16* __restrict__ lg, float* __restrict__ s) {
  int t = threadIdx.x, l = t & 63, w = t >> 6;
  // fused s-zero: 65536 floats / 64 blocks = 1024 each (v4f per thread)
  *(v4f*)(s + (size_t)blockIdx.x * 1024 + t * 4) = (v4f){0.f, 0.f, 0.f, 0.f};
  f16* p = lg + (size_t)blockIdx.x * 1032;
  float x[5];
  float mx = -3.4e38f;
#pragma unroll
  for (int i = 0; i < 5; i++) {
    int idx = t + i * 256;
    if (idx < 1032) { x[i] = (float)p[idx]; mx = fmaxf(mx, x[i]); }
  }
  __shared__ float sh[4];
#pragma unroll
  for (int o = 32; o; o >>= 1) mx = fmaxf(mx, __shfl_down(mx, o, 64));
  if (l == 0) sh[w] = mx;
  __syncthreads();
  mx = fmaxf(fmaxf(sh[0], sh[1]), fmaxf(sh[2], sh[3]));
  __syncthreads();
  float sum = 0.f;
#pragma unroll
  for (int i = 0; i < 5; i++) {
    int idx = t + i * 256;
    if (idx < 1032) { x[i] = expf(x[i] - mx); sum += x[i]; }
  }
  sum = wred_sum(sum);
  if (l == 0) sh[w] = sum;
  __syncthreads();
  float inv = 1.0f / (sh[0] + sh[1] + sh[2] + sh[3]);
#pragma unroll
  for (int i = 0; i < 5; i++) {
    int idx = t + i * 256;
    if (idx < 1032) p[idx] = (f16)(x[i] * inv);
  }
}

// ---------- S = P @ KV, p-split for latency hiding ----------
__global__ __launch_bounds__(256) void k_s(const f16* __restrict__ lg,
    const bf16* __restrict__ kvbuf, float* __restrict__ s) {
  int lin = blockIdx.x;              // 8b * 16kt * 8pc
  int b = lin >> 7, kt = (lin >> 3) & 15, pc = lin & 7;
  int t = threadIdx.x, l = t & 63, w = t >> 6;
  __shared__ f16 wl[8][132];         // 129 used
  __shared__ float red[4][8][64];    // 8KB
  for (int i = t; i < 8 * 129; i += 256) {
    int h = i / 129, pp = i % 129;
    wl[h][pp] = lg[(size_t)(b * 8 + h) * 1032 + pc * 129 + pp];
  }
  __syncthreads();
  int k = kt * 64 + l;
  const bf16* kvb = kvbuf + (size_t)b * 1032 * DD + k;
  float a0 = 0.f, a1 = 0.f, a2 = 0.f, a3 = 0.f, a4 = 0.f, a5 = 0.f, a6 = 0.f, a7 = 0.f;
#pragma unroll 4
  for (int pp = w; pp < 129; pp += 4) {
    int p = pc * 129 + pp;
    float kvv = (float)kvb[(size_t)p * DD];
    a0 += (float)wl[0][pp] * kvv;
    a1 += (float)wl[1][pp] * kvv;
    a2 += (float)wl[2][pp] * kvv;
    a3 += (float)wl[3][pp] * kvv;
    a4 += (float)wl[4][pp] * kvv;
    a5 += (float)wl[5][pp] * kvv;
    a6 += (float)wl[6][pp] * kvv;
    a7 += (float)wl[7][pp] * kvv;
  }
  red[w][0][l] = a0; red[w][1][l] = a1; red[w][2][l] = a2; red[w][3][l] = a3;
  red[w][4][l] = a4; red[w][5][l] = a5; red[w][6][l] = a6; red[w][7][l] = a7;
  __syncthreads();
  int hh = t >> 6;                   // 0..3, handles h=hh and h=hh+4
  float r0 = red[0][hh][l] + red[1][hh][l] + red[2][hh][l] + red[3][hh][l];
  float r1 = red[0][hh + 4][l] + red[1][hh + 4][l] + red[2][hh + 4][l] + red[3][hh + 4][l];
  atomicAdd(&s[(size_t)(b * 8 + hh) * DD + k], r0);
  atomicAdd(&s[(size_t)(b * 8 + hh + 4) * DD + k], r1);
}

__global__ __launch_bounds__(256) void k_ov(const float* __restrict__ s,
    const float* __restrict__ Wi, const float* __restrict__ bi, float* __restrict__ o) {
  int idx = blockIdx.x * 4 + (threadIdx.x >> 6);
  int l = threadIdx.x & 63;
  int b = idx >> 10, n = idx & 1023, h = n >> 7;
  const float* sr = s + (size_t)(b * 8 + h) * DD;
  const float* wr = Wi + (size_t)(2048 + n) * DD;
  float acc = 0.f;
#pragma unroll
  for (int k0 = 0; k0 < 1024; k0 += 64) acc += sr[k0 + l] * wr[k0 + l];
  acc = wred_sum(acc);
  if (l == 0) o[idx] = acc + bi[2048 + n];
}

// ---------- tail GEMVs ----------
template <int MODE>
__global__ __launch_bounds__(256) void k_gemv(const float* __restrict__ xin,
    const float* __restrict__ W, const float* __restrict__ bias,
    const float* __restrict__ res, float* __restrict__ outf) {
  int idx = blockIdx.x * 4 + (threadIdx.x >> 6);
  int l = threadIdx.x & 63;
  int b = idx >> 10, n = idx & 1023;
  const float* xr = xin + (size_t)b * DD;
  const float* wr = W + (size_t)n * DD;
  float acc = 0.f;
#pragma unroll
  for (int k0 = 0; k0 < 1024; k0 += 64) acc += xr[k0 + l] * wr[k0 + l];
  acc = wred_sum(acc);
  if (l == 0) {
    float v = acc + bias[n];
    if (MODE == 0) outf[idx] = res[idx] + v;
    if (MODE == 1) outf[idx] = 0.5f * v * (1.0f + erff(v * 0.70710678118654752f));
    if (MODE == 2) outf[idx] = res[idx] + v;
    if (MODE == 3) outf[O_Y + idx] = v;
  }
}

extern "C" void kernel_launch(void* const* d_in, const int* in_sizes, int n_in,
                              void* d_out, int out_size, void* d_ws, size_t ws_size,
                              hipStream_t stream) {
  const float* x        = (const float*)d_in[0];
  const float* state_in = (const float*)d_in[1];
  const float* W_rg     = (const float*)d_in[2];
  const float* ln_moe_g = (const float*)d_in[3];
  const float* ln_moe_b = (const float*)d_in[4];
  const float* W_gate   = (const float*)d_in[5];
  const float* A_skew   = (const float*)d_in[6];
  const float* ln_sl_g  = (const float*)d_in[7];
  const float* ln_sl_b  = (const float*)d_in[8];
  const float* W_slot   = (const float*)d_in[9];
  const float* W_oe     = (const float*)d_in[10];
  const float* b_oe     = (const float*)d_in[11];
  const float* ln_q_g   = (const float*)d_in[12];
  const float* ln_q_b   = (const float*)d_in[13];
  const float* ln_kv_g  = (const float*)d_in[14];
  const float* ln_kv_b  = (const float*)d_in[15];
  const float* in_w     = (const float*)d_in[16];
  const float* in_b     = (const float*)d_in[17];
  const float* out_w    = (const float*)d_in[18];
  const float* out_b    = (const float*)d_in[19];
  const float* ln_f_g   = (const float*)d_in[20];
  const float* ln_f_b   = (const float*)d_in[21];
  const float* W_fc1    = (const float*)d_in[22];
  const float* b_fc1    = (const float*)d_in[23];
  const float* W_fc2    = (const float*)d_in[24];
  const float* b_fc2    = (const float*)d_in[25];
  const float* W_out    = (const float*)d_in[26];
  const float* b_out    = (const float*)d_in[27];

  char* ws = (char*)d_ws;
  bf16*  kvbuf    = (bf16*)(ws + W_KV);
  float* state_ws = (float*)(ws + W_STATE);
  float* u_buf    = (float*)(ws + W_STATE);
  float* s_f32    = (float*)(ws + W_STATE);   // aliases u (dead after k_lg)
  float* lat_last = (float*)(ws + W_LATL);
  float* qln      = (float*)(ws + W_QLN);
  float* c0       = (float*)(ws + W_QLN);     // qln dead after k_qp
  float* r2       = (float*)(ws + W_R2);
  float* rsc      = (float*)(ws + W_RSC);
  float* ssc      = (float*)(ws + W_SSC);
  float* qp       = (float*)(ws + W_OATT);
  f16*   lg       = (f16*)(ws + W_OATT);
  float* o_attn   = (float*)(ws + W_OATT);
  float* lat1     = (float*)(ws + W_LAT1);
  float* lnffn    = (float*)(ws + W_LNFFN);
  float* h1       = (float*)(ws + W_H1);
  float* lat2     = (float*)(ws + W_LAT2);
  float* out = (float*)d_out;

  k_rs<<<1088, 256, 0, stream>>>(A_skew, r2, state_in, W_rg, ln_sl_g, ln_sl_b, W_slot, rsc, ssc);
  k_gate<<<32, 256, 0, stream>>>(state_in, rsc, ln_moe_g, ln_moe_b, W_gate, out);
  k_state<<<8, 256, 0, stream>>>(state_in, rsc, ssc, r2, state_ws, out);
  k_gemm<<<dim3(8, 64), 512, 0, stream>>>(x, W_oe, b_oe, kvbuf, lat_last);
  k_ln<<<8256, 256, 0, stream>>>(kvbuf, state_ws, ln_kv_g, ln_kv_b, ln_q_g, ln_q_b, qln, lat_last);
  k_qp<<<2048, 256, 0, stream>>>(qln, in_w, in_b, qp);
  k_u<<<128, 1024, 0, stream>>>(qp, in_w, in_b, u_buf, c0);
  k_lg<<<264, 256, 0, stream>>>(u_buf, kvbuf, c0, lg);
  k_sm<<<64, 256, 0, stream>>>(lg, s_f32);
  k_s<<<1024, 256, 0, stream>>>(lg, kvbuf, s_f32);
  k_ov<<<2048, 256, 0, stream>>>(s_f32, in_w, in_b, o_attn);
  k_gemv<0><<<2048, 256, 0, stream>>>(o_attn, out_w, out_b, lat_last, lat1);
  k_ln_row<<<8, 256, 0, stream>>>(lat1, ln_f_g, ln_f_b, lnffn);
  k_gemv<1><<<2048, 256, 0, stream>>>(lnffn, W_fc1, b_fc1, nullptr, h1);
  k_gemv<2><<<2048, 256, 0, stream>>>(h1, W_fc2, b_fc2, lat1, lat2);
  k_gemv<3><<<2048, 256, 0, stream>>>(lat2, W_out, b_out, nullptr, out);
}

// Round 16
// 280.831 us; speedup vs baseline: 1.1925x; 1.0245x over previous
//
#include <hip/hip_runtime.h>
#include <hip/hip_bf16.h>

typedef __bf16 bf16;
typedef _Float16 f16;
typedef __bf16 v8bf __attribute__((ext_vector_type(8)));
typedef float v4f __attribute__((ext_vector_type(4)));

// ---------- constants ----------
#define DD 1024
#define LN_EPS 1e-5f

// output element offsets (all f32 in d_out)
#define O_Y     0
#define O_STATE 8192
#define O_IDXE  73728
#define O_RIDX  73792
#define O_WIDX  73824

// ws byte offsets (total 17404416 B — exact layout, proven in-bounds)
#define W_KV      0ull                      // bf16 [8][1032][1024] 16908288
#define W_STATE   16908288ull               // f32  [8][8][1024]      262144 (PoolA: state -> u -> s(f32))
#define W_LATL    17170432ull               // f32  [8][1024]          32768
#define W_QLN     17203200ull               // f32  [8][1024]  (c0[64] reuses after k_qp)
#define W_R2      17235968ull               // f32  [1024]
#define W_RSC     17240064ull               // f32  [64]
#define W_SSC     17240320ull               // f32  [64]
#define W_OATT    17240576ull               // PoolB 160KB: qp / lg(f16 132KB) / o_attn+lat1..lat2
#define W_LAT1    17273344ull
#define W_LNFFN   17306112ull
#define W_H1      17338880ull
#define W_LAT2    17371648ull

__device__ __forceinline__ float wred_sum(float v) {
#pragma unroll
  for (int o = 32; o; o >>= 1) v += __shfl_down(v, o, 64);
  return v;
}

__device__ __forceinline__ void top4_of8(const float* sc, int* ridx) {
  unsigned used = 0;
#pragma unroll
  for (int k = 0; k < 4; k++) {
    float best = -3.4e38f; int bi = 0;
    for (int s = 0; s < 8; s++)
      if (!((used >> s) & 1) && sc[s] > best) { best = sc[s]; bi = s; }
    used |= 1u << bi; ridx[k] = bi;
  }
}

// ---------- fused: r2 row norms (blocks 0..1023) + read/slot scores (blocks 1024..1087) ----------
__global__ __launch_bounds__(256) void k_rs(const float* __restrict__ A, float* __restrict__ r2,
    const float* __restrict__ state, const float* __restrict__ W_rg,
    const float* __restrict__ g_sl, const float* __restrict__ b_sl,
    const float* __restrict__ W_sl, float* __restrict__ rsc, float* __restrict__ ssc) {
  int t = threadIdx.x, l = t & 63, w = t >> 6;
  if (blockIdx.x < 1024) {
    int row = blockIdx.x;
    const float* p = A + (size_t)row * DD;
    float s = 0.f;
    for (int j = t; j < DD; j += 256) { float x = p[j]; s += x * x; }
    s = wred_sum(s);
    __shared__ float sh1[4];
    if (l == 0) sh1[w] = s;
    __syncthreads();
    if (t == 0) r2[row] = sh1[0] + sh1[1] + sh1[2] + sh1[3];
    return;
  }
  int row = blockIdx.x - 1024;
  const float* p = state + (size_t)row * DD;
  float x[4]; float sum = 0.f, sq = 0.f, rs = 0.f;
#pragma unroll
  for (int i = 0; i < 4; i++) {
    int j = t + i * 256;
    x[i] = p[j];
    sum += x[i]; sq += x[i] * x[i];
    rs += x[i] * W_rg[j];
  }
  __shared__ float sh[3][4];
  sum = wred_sum(sum); sq = wred_sum(sq); rs = wred_sum(rs);
  if (l == 0) { sh[0][w] = sum; sh[1][w] = sq; sh[2][w] = rs; }
  __syncthreads();
  float m = (sh[0][0] + sh[0][1] + sh[0][2] + sh[0][3]) * (1.0f / 1024.0f);
  float var = (sh[1][0] + sh[1][1] + sh[1][2] + sh[1][3]) * (1.0f / 1024.0f) - m * m;
  float rsTot = sh[2][0] + sh[2][1] + sh[2][2] + sh[2][3];
  float inv = 1.0f / sqrtf(var + LN_EPS);
  __syncthreads();
  float ss = 0.f;
#pragma unroll
  for (int i = 0; i < 4; i++) {
    int j = t + i * 256;
    float ln = (x[i] - m) * inv * g_sl[j] + b_sl[j];
    ss += ln * W_sl[j];
  }
  ss = wred_sum(ss);
  if (l == 0) sh[0][w] = ss;
  __syncthreads();
  if (t == 0) { rsc[row] = rsTot; ssc[row] = sh[0][0] + sh[0][1] + sh[0][2] + sh[0][3]; }
}

// ---------- fused gate (blocks 0..31) + state update (blocks 32..39) ----------
// Both depend only on rsc/ssc/r2 (from k_rs) and are mutually independent:
// gate writes out[idx_experts,read_idx]; state writes state_ws + out[state,widx].
// Fusing saves one launch. Bodies are round-12-exact.
__global__ __launch_bounds__(256) void k_gs(const float* __restrict__ state,
    const float* __restrict__ rsc, const float* __restrict__ ssc, const float* __restrict__ r2,
    const float* __restrict__ g_moe, const float* __restrict__ b_moe,
    const float* __restrict__ Wg, float* __restrict__ state_ws, float* __restrict__ out) {
  int t = threadIdx.x, l = t & 63, w = t >> 6;
  if (blockIdx.x < 32) {
    // ---- gate part ----
    int b = blockIdx.x >> 2, k = blockIdx.x & 3;
    __shared__ float rs[8];
    __shared__ float red[2][4];
    __shared__ float gl[8];
    if (t < 8) rs[t] = rsc[b * 8 + t];
    __syncthreads();
    int ridx[4]; top4_of8(rs, ridx);
    int s = ridx[k];
    const float* p = state + (size_t)(b * 8 + s) * DD;
    float x[4]; float sum = 0.f, sq = 0.f;
#pragma unroll
    for (int i = 0; i < 4; i++) {
      int j = t + i * 256;
      x[i] = p[j]; sum += x[i]; sq += x[i] * x[i];
    }
    sum = wred_sum(sum); sq = wred_sum(sq);
    if (l == 0) { red[0][w] = sum; red[1][w] = sq; }
    __syncthreads();
    float m = (red[0][0] + red[0][1] + red[0][2] + red[0][3]) * (1.0f / 1024.0f);
    float var = (red[1][0] + red[1][1] + red[1][2] + red[1][3]) * (1.0f / 1024.0f) - m * m;
    float inv = 1.0f / sqrtf(var + LN_EPS);
    float lnv[4];
#pragma unroll
    for (int i = 0; i < 4; i++) {
      int j = t + i * 256;
      lnv[i] = (x[i] - m) * inv * g_moe[j] + b_moe[j];
    }
    __syncthreads();
    for (int e = 0; e < 8; e++) {
      float acc = 0.f;
#pragma unroll
      for (int i = 0; i < 4; i++) acc += lnv[i] * Wg[(size_t)e * DD + t + i * 256];
      acc = wred_sum(acc);
      if (l == 0) red[0][w] = acc;
      __syncthreads();
      if (t == 0) gl[e] = red[0][0] + red[0][1] + red[0][2] + red[0][3];
      __syncthreads();
    }
    if (t == 0) {
      int e0 = 0, e1 = 0; float b0 = -3.4e38f, b1 = -3.4e38f;
      for (int e = 0; e < 8; e++) {
        float v = gl[e];
        if (v > b0) { b1 = b0; e1 = e0; b0 = v; e0 = e; }
        else if (v > b1) { b1 = v; e1 = e; }
      }
      out[O_IDXE + (b * 4 + k) * 2 + 0] = (float)e0;
      out[O_IDXE + (b * 4 + k) * 2 + 1] = (float)e1;
      if (k == 0)
        for (int kk = 0; kk < 4; kk++) out[O_RIDX + b * 4 + kk] = (float)ridx[kk];
    }
    return;
  }
  // ---- state part ----
  int b = blockIdx.x - 32;
  __shared__ float rs2[8];
  if (t < 8) rs2[t] = rsc[b * 8 + t];
  __syncthreads();
  int ridx[4]; top4_of8(rs2, ridx);
  float lr[4];
#pragma unroll
  for (int k = 0; k < 4; k++) lr[k] = ssc[b * 8 + ridx[k]];
  int w0 = 0, w1 = 0; float b0 = -3.4e38f, b1 = -3.4e38f;
#pragma unroll
  for (int k = 0; k < 4; k++) {
    float v = lr[k];
    if (v > b0) { b1 = b0; w1 = w0; b0 = v; w0 = k; }
    else if (v > b1) { b1 = v; w1 = k; }
  }
  int wid0 = ridx[w0], wid1 = ridx[w1];
  float mx = fmaxf(lr[0], lr[1]);
  float e0 = expf(lr[0] - mx), e1 = expf(lr[1] - mx);
  float den = e0 + e1;
  float ws0 = e0 / den, ws1 = e1 / den;
  float resid = 1.0f - (ws0 + ws1);
#pragma unroll
  for (int i = 0; i < 4; i++) {
    int j = t + i * 256;
    float q = 1.0f - 0.03125f * r2[j];  // diag Cayley, c=0.125, O(c^4) dropped
    float lca = 0.f;
#pragma unroll
    for (int k = 0; k < 4; k++)
      lca += tanhf(state[(size_t)(b * 8 + ridx[k]) * DD + j] * q);
    float tj = tanhf(lca * 0.25f);
#pragma unroll
    for (int s = 0; s < 8; s++) {
      float a = (s == wid0) ? ws0 : ((s == wid1) ? ws1 : 0.0f);
      float v = a * tj + resid * state[(size_t)(b * 8 + s) * DD + j];
      state_ws[(size_t)(b * 8 + s) * DD + j] = v;
      out[O_STATE + (size_t)(b * 8 + s) * DD + j] = v;
    }
  }
  if (t == 0) {
    out[O_WIDX + b * 2 + 0] = (float)wid0;
    out[O_WIDX + b * 2 + 1] = (float)wid1;
  }
}

// ---------- MFMA BT GEMM — round-9 exact (plateau established; do not touch) ----------
#define MF(CC, AF, BF) CC = __builtin_amdgcn_mfma_f32_16x16x32_bf16(AF, BF, CC, 0, 0, 0)

__device__ __forceinline__ v4f gload4(const float* p) {
  v4f r;
  asm volatile("global_load_dwordx4 %0, %1, off" : "=v"(r) : "v"(p));
  return r;
}

__global__ __launch_bounds__(512, 4) void k_gemm(const float* __restrict__ A,
    const float* __restrict__ Bm, const float* __restrict__ bias, bf16* __restrict__ kvbuf,
    float* __restrict__ lat_last) {
  __shared__ bf16 smem[4][128 * 32];   // [0]=A-buf0 [1]=A-buf1 [2]=B-buf0 [3]=B-buf1
  const int t = threadIdx.x, l = t & 63, w = t >> 6;   // w: 0..7
  const int lin = blockIdx.y * 8 + blockIdx.x;
  const int mb = ((lin & 7) << 3) | ((lin >> 3) & 7);  // 8 A-band blocks per XCD
  const int nb = lin >> 6;
  const int mbase = mb * 128, nbase = nb * 128;
  const int wm = (w >> 1) * 32, wn = (w & 1) * 64;     // wave tile 32x64
  const int lm = l & 15, lk4 = l >> 4;

  v4f c00 = (v4f){0.f,0.f,0.f,0.f}, c01 = (v4f){0.f,0.f,0.f,0.f},
      c02 = (v4f){0.f,0.f,0.f,0.f}, c03 = (v4f){0.f,0.f,0.f,0.f},
      c10 = (v4f){0.f,0.f,0.f,0.f}, c11 = (v4f){0.f,0.f,0.f,0.f},
      c12 = (v4f){0.f,0.f,0.f,0.f}, c13 = (v4f){0.f,0.f,0.f,0.f};

  const int srow = t >> 2;          // 0..127 (one LDS row per thread)
  const int sch = t & 3;            // k-chunk of 8
  const int swA = srow * 32 + (sch ^ ((srow >> 1) & 3)) * 8;
  const int fa_base = (wm + lm) * 32 + ((lk4 ^ ((lm >> 1) & 3)) * 8);
  const int fb_base = (wn + lm) * 32 + ((lk4 ^ ((lm >> 1) & 3)) * 8);

  const float* aRow = A + (size_t)(mbase + srow) * 1024 + sch * 8;
  const float* bRow = Bm + (size_t)(nbase + srow) * 1024 + sch * 8;

  // prologue: issue k-chunk 0 (in flight until first half1's vmcnt(4))
  v4f a0 = gload4(aRow), a1 = gload4(aRow + 4);
  v4f b0 = gload4(bRow), b1 = gload4(bRow + 4);
  v4f na0, na1, nb0, nb1;

#define STAGE_AND_MFMA(AV0, AV1, BV0, BV1, AB, BB) do { \
    v8bf pa, pb; \
    _Pragma("unroll") \
    for (int r = 0; r < 4; r++) { pa[r] = (bf16)AV0[r]; pa[4 + r] = (bf16)AV1[r]; } \
    _Pragma("unroll") \
    for (int r = 0; r < 4; r++) { pb[r] = (bf16)BV0[r]; pb[4 + r] = (bf16)BV1[r]; } \
    *(v8bf*)(AB + swA) = pa; \
    *(v8bf*)(BB + swA) = pb; \
    asm volatile("s_waitcnt lgkmcnt(0)" ::: "memory"); \
    __builtin_amdgcn_s_barrier(); \
    asm volatile("" ::: "memory"); \
    v8bf af0 = *(const v8bf*)(AB + fa_base); \
    v8bf af1 = *(const v8bf*)(AB + fa_base + 512); \
    v8bf bq0 = *(const v8bf*)(BB + fb_base); \
    v8bf bq1 = *(const v8bf*)(BB + fb_base + 512); \
    v8bf bq2 = *(const v8bf*)(BB + fb_base + 1024); \
    v8bf bq3 = *(const v8bf*)(BB + fb_base + 1536); \
    MF(c00, af0, bq0); MF(c01, af0, bq1); MF(c02, af0, bq2); MF(c03, af0, bq3); \
    MF(c10, af1, bq0); MF(c11, af1, bq1); MF(c12, af1, bq2); MF(c13, af1, bq3); \
  } while (0)

  for (int k0 = 0; k0 < 1024; k0 += 64) {
    // ---- half 1: consume a* (chunk k0), prefetch na* (chunk k0+32) ----
    {
      const int kn = k0 + 32;
      na0 = gload4(aRow + kn); na1 = gload4(aRow + kn + 4);
      nb0 = gload4(bRow + kn); nb1 = gload4(bRow + kn + 4);
      asm volatile("s_waitcnt vmcnt(4)" : "+v"(a0), "+v"(a1), "+v"(b0), "+v"(b1));
      STAGE_AND_MFMA(a0, a1, b0, b1, (&smem[0][0]), (&smem[2][0]));
    }
    // ---- half 2: consume na* (chunk k0+32), prefetch a* (chunk k0+64) ----
    {
      const int kn = (k0 + 64 < 1024) ? (k0 + 64) : k0;  // last: harmless reload
      a0 = gload4(aRow + kn); a1 = gload4(aRow + kn + 4);
      b0 = gload4(bRow + kn); b1 = gload4(bRow + kn + 4);
      asm volatile("s_waitcnt vmcnt(4)" : "+v"(na0), "+v"(na1), "+v"(nb0), "+v"(nb1));
      STAGE_AND_MFMA(na0, na1, nb0, nb1, (&smem[1][0]), (&smem[3][0]));
    }
  }
#undef STAGE_AND_MFMA
  // drain the 4 dangling prefetch loads WITH TIES (round-8 lesson: keeps dest regs
  // live past the drain so the allocator cannot hand them to epilogue values).
  asm volatile("s_waitcnt vmcnt(0)" : "+v"(a0), "+v"(a1), "+v"(b0), "+v"(b1));

  // ---- epilogue: full 128x128 bf16 tile in LDS (all 32KB), then coalesced flush ----
  bf16* ot = &smem[0][0];             // 16384 bf16 = [128][128]
  const int er = (l >> 4) * 4;
  __syncthreads();                    // all K-loop LDS reads done

#define EPI_ONE(ii, jj, CC) do { \
    _Pragma("unroll") \
    for (int r = 0; r < 4; r++) { \
      int lrow = wm + (ii) * 16 + er + r; \
      int lcol = wn + (jj) * 16 + lm; \
      int grow = mbase + lrow; \
      int col = nbase + lcol; \
      int tok = grow & 1023, bb = grow >> 10; \
      int i2 = col & 511; \
      float fdiv = exp2f((float)i2 * (3.0f / 512.0f)); \
      float aarg = (float)tok / fdiv; \
      float pe = (col < 512) ? sinf(aarg) : cosf(aarg); \
      float v = CC[r] + bias[col] + pe; \
      ot[lrow * 128 + lcol] = (bf16)v; \
      if (tok == 1023) lat_last[(size_t)bb * 1024 + col] = v; \
    } \
  } while (0)

  EPI_ONE(0, 0, c00); EPI_ONE(0, 1, c01); EPI_ONE(0, 2, c02); EPI_ONE(0, 3, c03);
  EPI_ONE(1, 0, c10); EPI_ONE(1, 1, c11); EPI_ONE(1, 2, c12); EPI_ONE(1, 3, c13);
#undef EPI_ONE
  __syncthreads();
  {
    int rr = t >> 2;                  // 0..127
    int cc = (t & 3) * 32;            // 0,32,64,96
    int grow = mbase + rr;
    int tok = grow & 1023, bb = grow >> 10;
    bf16* dst = kvbuf + ((size_t)bb * 1032 + tok) * 1024 + nbase + cc;
    v8bf d0 = *(const v8bf*)(ot + rr * 128 + cc);
    v8bf d1 = *(const v8bf*)(ot + rr * 128 + cc + 8);
    v8bf d2 = *(const v8bf*)(ot + rr * 128 + cc + 16);
    v8bf d3 = *(const v8bf*)(ot + rr * 128 + cc + 24);
    *(v8bf*)dst = d0;
    *(v8bf*)(dst + 8) = d1;
    *(v8bf*)(dst + 16) = d2;
    *(v8bf*)(dst + 24) = d3;
  }
}

// ---------- LN (in-place on kv token rows; state rows from f32; q row from f32 lat_last) ----------
__global__ __launch_bounds__(256) void k_ln(bf16* __restrict__ kvbuf,
    const float* __restrict__ state_ws, const float* __restrict__ gkv, const float* __restrict__ bkv,
    const float* __restrict__ gq, const float* __restrict__ bq,
    float* __restrict__ qln, const float* __restrict__ lat_last) {
  int r = blockIdx.x, t = threadIdx.x, l = t & 63, w = t >> 6;
  int b = r / 1032, p = r % 1032;
  bf16* row = kvbuf + ((size_t)b * 1032 + p) * DD;
  float x[4]; float sum = 0.f, sq = 0.f;
  if (p == 1023) {
    const float* src = lat_last + (size_t)b * DD;
#pragma unroll
    for (int i = 0; i < 4; i++) {
      int j = t + i * 256;
      x[i] = src[j]; sum += x[i]; sq += x[i] * x[i];
    }
  } else if (p < 1024) {
#pragma unroll
    for (int i = 0; i < 4; i++) {
      int j = t + i * 256;
      x[i] = (float)row[j]; sum += x[i]; sq += x[i] * x[i];
    }
  } else {
    const float* src = state_ws + ((size_t)b * 8 + (p - 1024)) * DD;
#pragma unroll
    for (int i = 0; i < 4; i++) {
      int j = t + i * 256;
      x[i] = src[j]; sum += x[i]; sq += x[i] * x[i];
    }
  }
  __shared__ float sh[2][4];
  sum = wred_sum(sum); sq = wred_sum(sq);
  if (l == 0) { sh[0][w] = sum; sh[1][w] = sq; }
  __syncthreads();
  float m = (sh[0][0] + sh[0][1] + sh[0][2] + sh[0][3]) * (1.0f / 1024.0f);
  float var = (sh[1][0] + sh[1][1] + sh[1][2] + sh[1][3]) * (1.0f / 1024.0f) - m * m;
  float inv = 1.0f / sqrtf(var + LN_EPS);
  if (p == 1023) {
#pragma unroll
    for (int i = 0; i < 4; i++) {
      int j = t + i * 256;
      qln[(size_t)b * DD + j] = (x[i] - m) * inv * gq[j] + bq[j];
    }
  }
#pragma unroll
  for (int i = 0; i < 4; i++) {
    int j = t + i * 256;
    row[j] = (bf16)((x[i] - m) * inv * gkv[j] + bkv[j]);
  }
}

// ---------- LN of one f32 row per block (ffn pre-LN) ----------
__global__ __launch_bounds__(256) void k_ln_row(const float* __restrict__ src,
    const float* __restrict__ g, const float* __restrict__ bb, float* __restrict__ dst) {
  int b = blockIdx.x, t = threadIdx.x, l = t & 63, w = t >> 6;
  const float* p = src + (size_t)b * DD;
  float x[4]; float sum = 0.f, sq = 0.f;
#pragma unroll
  for (int i = 0; i < 4; i++) {
    int j = t + i * 256;
    x[i] = p[j]; sum += x[i]; sq += x[i] * x[i];
  }
  __shared__ float sh[2][4];
  sum = wred_sum(sum); sq = wred_sum(sq);
  if (l == 0) { sh[0][w] = sum; sh[1][w] = sq; }
  __syncthreads();
  float m = (sh[0][0] + sh[0][1] + sh[0][2] + sh[0][3]) * (1.0f / 1024.0f);
  float var = (sh[1][0] + sh[1][1] + sh[1][2] + sh[1][3]) * (1.0f / 1024.0f) - m * m;
  float inv = 1.0f / sqrtf(var + LN_EPS);
#pragma unroll
  for (int i = 0; i < 4; i++) {
    int j = t + i * 256;
    dst[(size_t)b * DD + j] = (x[i] - m) * inv * g[j] + bb[j];
  }
}

// ---------- attention pipeline (round-12 per-wave GEMV forms — measured best) ----------
__global__ __launch_bounds__(256) void k_qp(const float* __restrict__ qln,
    const float* __restrict__ Wi, const float* __restrict__ bi, float* __restrict__ qp) {
  int idx = blockIdx.x * 4 + (threadIdx.x >> 6);
  int l = threadIdx.x & 63;
  int b = idx >> 10, n = idx & 1023;
  const float* xr = qln + (size_t)b * DD;
  const float* wr = Wi + (size_t)n * DD;
  float acc = 0.f;
#pragma unroll
  for (int k0 = 0; k0 < 1024; k0 += 64) acc += xr[k0 + l] * wr[k0 + l];
  acc = wred_sum(acc);
  if (l == 0) qp[idx] = acc + bi[n];
}

// ---------- u = q-heads @ Wk^T, 1024-thread (4x d-split); fuses c0 on kt==0 ----------
__global__ __launch_bounds__(1024) void k_u(const float* __restrict__ qp,
    const float* __restrict__ Wi, const float* __restrict__ bi,
    float* __restrict__ u, float* __restrict__ c0) {
  int h = blockIdx.x >> 4, kt = blockIdx.x & 15;
  int t = threadIdx.x;
  __shared__ float qs[8][128];
  __shared__ float red[4][4][2][64];   // [dc][bh][a0/a1][k-lane] 8KB
  {
    int b = t >> 7, d = t & 127;
    qs[b][d] = qp[b * 1024 + h * 128 + d];
  }
  __syncthreads();
  int kl = t & 63;
  int k = kt * 64 + kl;
  int bh = (t >> 6) & 3;
  int dc = t >> 8;                     // 0..3
  const float* wkb = Wi + (size_t)(1024 + h * 128 + dc * 32) * DD + k;
  float a0 = 0.f, a1 = 0.f;
#pragma unroll 8
  for (int d = 0; d < 32; d++) {
    float wv = wkb[(size_t)d * DD];
    a0 += qs[bh][dc * 32 + d] * wv;
    a1 += qs[bh + 4][dc * 32 + d] * wv;
  }
  red[dc][bh][0][kl] = a0;
  red[dc][bh][1][kl] = a1;
  __syncthreads();
  if (dc == 0) {
    float s0 = red[0][bh][0][kl] + red[1][bh][0][kl] + red[2][bh][0][kl] + red[3][bh][0][kl];
    float s1 = red[0][bh][1][kl] + red[1][bh][1][kl] + red[2][bh][1][kl] + red[3][bh][1][kl];
    u[(size_t)(bh * 8 + h) * DD + k] = s0;
    u[(size_t)((bh + 4) * 8 + h) * DD + k] = s1;
  }
  // fused c0 (only 8 blocks do this): c0[b*8+h] = dot128(qp[b,h-slice], bi[1024+h-slice])
  if (kt == 0 && t < 512) {
    int b = t >> 6;
    float a = qp[b * 1024 + h * 128 + kl] * bi[1024 + h * 128 + kl]
            + qp[b * 1024 + h * 128 + 64 + kl] * bi[1024 + h * 128 + 64 + kl];
    a = wred_sum(a);
    if (kl == 0) c0[b * 8 + h] = a;
  }
}

__global__ __launch_bounds__(256) void k_lg(const float* __restrict__ u,
    const bf16* __restrict__ kvbuf, const float* __restrict__ c0, f16* __restrict__ lg) {
  int b = blockIdx.x / 33, tile = blockIdx.x % 33;
  int p0 = tile * 32, t = threadIdx.x;
  __shared__ bf16 kvs[32 * 1032];
  __shared__ float us[8 * 1032];
  const bf16* kvb = kvbuf + (size_t)b * 1032 * DD;
#pragma unroll
  for (int i = 0; i < 16; i++) {
    int flat = (i * 256 + t) * 8;
    int row = flat >> 10, col = flat & 1023;
    int gp = p0 + row; if (gp > 1031) gp = 1031;
    *(v8bf*)(kvs + row * 1032 + col) = *(const v8bf*)(kvb + (size_t)gp * DD + col);
  }
#pragma unroll
  for (int i = 0; i < 8; i++) {
    int flat = (i * 256 + t) * 4;
    int row = flat >> 10, col = flat & 1023;
    *(v4f*)(us + row * 1032 + col) = *(const v4f*)(u + (size_t)(b * 8 + row) * DD + col);
  }
  __syncthreads();
  int pl = t >> 3, h = t & 7;
  if (p0 + pl < 1032) {
    float acc = 0.f;
#pragma unroll
    for (int k = 0; k < 1024; k += 8) {
      v8bf kv8 = *(const v8bf*)(kvs + pl * 1032 + k);
#pragma unroll
      for (int j = 0; j < 8; j++) acc += us[h * 1032 + k + j] * (float)kv8[j];
    }
    lg[(size_t)(b * 8 + h) * 1032 + p0 + pl] =
        (f16)((acc + c0[b * 8 + h]) * 0.08838834764831845f);
  }
}

// ---------- softmax; fuses zeroing of the f32 S buffer (s aliases u, dead after k_lg) ----------
__global__ __launch_bounds__(256) void k_sm(f16* __restrict__ lg, float* __restrict__ s) {
  int t = threadIdx.x, l = t & 63, w = t >> 6;
  // fused s-zero: 65536 floats / 64 blocks = 1024 each (v4f per thread)
  *(v4f*)(s + (size_t)blockIdx.x * 1024 + t * 4) = (v4f){0.f, 0.f, 0.f, 0.f};
  f16* p = lg + (size_t)blockIdx.x * 1032;
  float x[5];
  float mx = -3.4e38f;
#pragma unroll
  for (int i = 0; i < 5; i++) {
    int idx = t + i * 256;
    if (idx < 1032) { x[i] = (float)p[idx]; mx = fmaxf(mx, x[i]); }
  }
  __shared__ float sh[4];
#pragma unroll
  for (int o = 32; o; o >>= 1) mx = fmaxf(mx, __shfl_down(mx, o, 64));
  if (l == 0) sh[w] = mx;
  __syncthreads();
  mx = fmaxf(fmaxf(sh[0], sh[1]), fmaxf(sh[2], sh[3]));
  __syncthreads();
  float sum = 0.f;
#pragma unroll
  for (int i = 0; i < 5; i++) {
    int idx = t + i * 256;
    if (idx < 1032) { x[i] = expf(x[i] - mx); sum += x[i]; }
  }
  sum = wred_sum(sum);
  if (l == 0) sh[w] = sum;
  __syncthreads();
  float inv = 1.0f / (sh[0] + sh[1] + sh[2] + sh[3]);
#pragma unroll
  for (int i = 0; i < 5; i++) {
    int idx = t + i * 256;
    if (idx < 1032) p[idx] = (f16)(x[i] * inv);
  }
}

// ---------- S = P @ KV, p-split for latency hiding ----------
__global__ __launch_bounds__(256) void k_s(const f16* __restrict__ lg,
    const bf16* __restrict__ kvbuf, float* __restrict__ s) {
  int lin = blockIdx.x;              // 8b * 16kt * 8pc
  int b = lin >> 7, kt = (lin >> 3) & 15, pc = lin & 7;
  int t = threadIdx.x, l = t & 63, w = t >> 6;
  __shared__ f16 wl[8][132];         // 129 used
  __shared__ float red[4][8][64];    // 8KB
  for (int i = t; i < 8 * 129; i += 256) {
    int h = i / 129, pp = i % 129;
    wl[h][pp] = lg[(size_t)(b * 8 + h) * 1032 + pc * 129 + pp];
  }
  __syncthreads();
  int k = kt * 64 + l;
  const bf16* kvb = kvbuf + (size_t)b * 1032 * DD + k;
  float a0 = 0.f, a1 = 0.f, a2 = 0.f, a3 = 0.f, a4 = 0.f, a5 = 0.f, a6 = 0.f, a7 = 0.f;
#pragma unroll 4
  for (int pp = w; pp < 129; pp += 4) {
    int p = pc * 129 + pp;
    float kvv = (float)kvb[(size_t)p * DD];
    a0 += (float)wl[0][pp] * kvv;
    a1 += (float)wl[1][pp] * kvv;
    a2 += (float)wl[2][pp] * kvv;
    a3 += (float)wl[3][pp] * kvv;
    a4 += (float)wl[4][pp] * kvv;
    a5 += (float)wl[5][pp] * kvv;
    a6 += (float)wl[6][pp] * kvv;
    a7 += (float)wl[7][pp] * kvv;
  }
  red[w][0][l] = a0; red[w][1][l] = a1; red[w][2][l] = a2; red[w][3][l] = a3;
  red[w][4][l] = a4; red[w][5][l] = a5; red[w][6][l] = a6; red[w][7][l] = a7;
  __syncthreads();
  int hh = t >> 6;                   // 0..3, handles h=hh and h=hh+4
  float r0 = red[0][hh][l] + red[1][hh][l] + red[2][hh][l] + red[3][hh][l];
  float r1 = red[0][hh + 4][l] + red[1][hh + 4][l] + red[2][hh + 4][l] + red[3][hh + 4][l];
  atomicAdd(&s[(size_t)(b * 8 + hh) * DD + k], r0);
  atomicAdd(&s[(size_t)(b * 8 + hh + 4) * DD + k], r1);
}

__global__ __launch_bounds__(256) void k_ov(const float* __restrict__ s,
    const float* __restrict__ Wi, const float* __restrict__ bi, float* __restrict__ o) {
  int idx = blockIdx.x * 4 + (threadIdx.x >> 6);
  int l = threadIdx.x & 63;
  int b = idx >> 10, n = idx & 1023, h = n >> 7;
  const float* sr = s + (size_t)(b * 8 + h) * DD;
  const float* wr = Wi + (size_t)(2048 + n) * DD;
  float acc = 0.f;
#pragma unroll
  for (int k0 = 0; k0 < 1024; k0 += 64) acc += sr[k0 + l] * wr[k0 + l];
  acc = wred_sum(acc);
  if (l == 0) o[idx] = acc + bi[2048 + n];
}

// ---------- tail GEMVs ----------
template <int MODE>
__global__ __launch_bounds__(256) void k_gemv(const float* __restrict__ xin,
    const float* __restrict__ W, const float* __restrict__ bias,
    const float* __restrict__ res, float* __restrict__ outf) {
  int idx = blockIdx.x * 4 + (threadIdx.x >> 6);
  int l = threadIdx.x & 63;
  int b = idx >> 10, n = idx & 1023;
  const float* xr = xin + (size_t)b * DD;
  const float* wr = W + (size_t)n * DD;
  float acc = 0.f;
#pragma unroll
  for (int k0 = 0; k0 < 1024; k0 += 64) acc += xr[k0 + l] * wr[k0 + l];
  acc = wred_sum(acc);
  if (l == 0) {
    float v = acc + bias[n];
    if (MODE == 0) outf[idx] = res[idx] + v;
    if (MODE == 1) outf[idx] = 0.5f * v * (1.0f + erff(v * 0.70710678118654752f));
    if (MODE == 2) outf[idx] = res[idx] + v;
    if (MODE == 3) outf[O_Y + idx] = v;
  }
}

extern "C" void kernel_launch(void* const* d_in, const int* in_sizes, int n_in,
                              void* d_out, int out_size, void* d_ws, size_t ws_size,
                              hipStream_t stream) {
  const float* x        = (const float*)d_in[0];
  const float* state_in = (const float*)d_in[1];
  const float* W_rg     = (const float*)d_in[2];
  const float* ln_moe_g = (const float*)d_in[3];
  const float* ln_moe_b = (const float*)d_in[4];
  const float* W_gate   = (const float*)d_in[5];
  const float* A_skew   = (const float*)d_in[6];
  const float* ln_sl_g  = (const float*)d_in[7];
  const float* ln_sl_b  = (const float*)d_in[8];
  const float* W_slot   = (const float*)d_in[9];
  const float* W_oe     = (const float*)d_in[10];
  const float* b_oe     = (const float*)d_in[11];
  const float* ln_q_g   = (const float*)d_in[12];
  const float* ln_q_b   = (const float*)d_in[13];
  const float* ln_kv_g  = (const float*)d_in[14];
  const float* ln_kv_b  = (const float*)d_in[15];
  const float* in_w     = (const float*)d_in[16];
  const float* in_b     = (const float*)d_in[17];
  const float* out_w    = (const float*)d_in[18];
  const float* out_b    = (const float*)d_in[19];
  const float* ln_f_g   = (const float*)d_in[20];
  const float* ln_f_b   = (const float*)d_in[21];
  const float* W_fc1    = (const float*)d_in[22];
  const float* b_fc1    = (const float*)d_in[23];
  const float* W_fc2    = (const float*)d_in[24];
  const float* b_fc2    = (const float*)d_in[25];
  const float* W_out    = (const float*)d_in[26];
  const float* b_out    = (const float*)d_in[27];

  char* ws = (char*)d_ws;
  bf16*  kvbuf    = (bf16*)(ws + W_KV);
  float* state_ws = (float*)(ws + W_STATE);
  float* u_buf    = (float*)(ws + W_STATE);
  float* s_f32    = (float*)(ws + W_STATE);   // aliases u (dead after k_lg)
  float* lat_last = (float*)(ws + W_LATL);
  float* qln      = (float*)(ws + W_QLN);
  float* c0       = (float*)(ws + W_QLN);     // qln dead after k_qp
  float* r2       = (float*)(ws + W_R2);
  float* rsc      = (float*)(ws + W_RSC);
  float* ssc      = (float*)(ws + W_SSC);
  float* qp       = (float*)(ws + W_OATT);
  f16*   lg       = (f16*)(ws + W_OATT);
  float* o_attn   = (float*)(ws + W_OATT);
  float* lat1     = (float*)(ws + W_LAT1);
  float* lnffn    = (float*)(ws + W_LNFFN);
  float* h1       = (float*)(ws + W_H1);
  float* lat2     = (float*)(ws + W_LAT2);
  float* out = (float*)d_out;

  k_rs<<<1088, 256, 0, stream>>>(A_skew, r2, state_in, W_rg, ln_sl_g, ln_sl_b, W_slot, rsc, ssc);
  k_gs<<<40, 256, 0, stream>>>(state_in, rsc, ssc, r2, ln_moe_g, ln_moe_b, W_gate, state_ws, out);
  k_gemm<<<dim3(8, 64), 512, 0, stream>>>(x, W_oe, b_oe, kvbuf, lat_last);
  k_ln<<<8256, 256, 0, stream>>>(kvbuf, state_ws, ln_kv_g, ln_kv_b, ln_q_g, ln_q_b, qln, lat_last);
  k_qp<<<2048, 256, 0, stream>>>(qln, in_w, in_b, qp);
  k_u<<<128, 1024, 0, stream>>>(qp, in_w, in_b, u_buf, c0);
  k_lg<<<264, 256, 0, stream>>>(u_buf, kvbuf, c0, lg);
  k_sm<<<64, 256, 0, stream>>>(lg, s_f32);
  k_s<<<1024, 256, 0, stream>>>(lg, kvbuf, s_f32);
  k_ov<<<2048, 256, 0, stream>>>(s_f32, in_w, in_b, o_attn);
  k_gemv<0><<<2048, 256, 0, stream>>>(o_attn, out_w, out_b, lat_last, lat1);
  k_ln_row<<<8, 256, 0, stream>>>(lat1, ln_f_g, ln_f_b, lnffn);
  k_gemv<1><<<2048, 256, 0, stream>>>(lnffn, W_fc1, b_fc1, nullptr, h1);
  k_gemv<2><<<2048, 256, 0, stream>>>(h1, W_fc2, b_fc2, lat1, lat2);
  k_gemv<3><<<2048, 256, 0, stream>>>(lat2, W_out, b_out, nullptr, out);
}

// Round 17
// 280.277 us; speedup vs baseline: 1.1949x; 1.0020x over previous
//
#include <hip/hip_runtime.h>
#include <hip/hip_bf16.h>

typedef __bf16 bf16;
typedef _Float16 f16;
typedef __bf16 v8bf __attribute__((ext_vector_type(8)));
typedef float v4f __attribute__((ext_vector_type(4)));

// ---------- constants ----------
#define DD 1024
#define LN_EPS 1e-5f

// output element offsets (all f32 in d_out)
#define O_Y     0
#define O_STATE 8192
#define O_IDXE  73728
#define O_RIDX  73792
#define O_WIDX  73824

// ws byte offsets (total 17404416 B — exact layout, proven in-bounds)
#define W_KV      0ull                      // bf16 [8][1032][1024] 16908288
#define W_STATE   16908288ull               // f32  [8][8][1024]      262144 (PoolA: state -> u -> s(f32))
#define W_LATL    17170432ull               // f32  [8][1024]          32768
#define W_QLN     17203200ull               // f32  [8][1024]  (c0[64] reuses after k_qp)
#define W_R2      17235968ull               // f32  [1024]
#define W_RSC     17240064ull               // f32  [64]
#define W_SSC     17240320ull               // f32  [64]
#define W_OATT    17240576ull               // PoolB 160KB: qp / lg(f16 132KB) / o_attn+lat1..lat2
#define W_LAT1    17273344ull
#define W_LNFFN   17306112ull
#define W_H1      17338880ull
#define W_LAT2    17371648ull

__device__ __forceinline__ float wred_sum(float v) {
#pragma unroll
  for (int o = 32; o; o >>= 1) v += __shfl_down(v, o, 64);
  return v;
}

__device__ __forceinline__ void top4_of8(const float* sc, int* ridx) {
  unsigned used = 0;
#pragma unroll
  for (int k = 0; k < 4; k++) {
    float best = -3.4e38f; int bi = 0;
    for (int s = 0; s < 8; s++)
      if (!((used >> s) & 1) && sc[s] > best) { best = sc[s]; bi = s; }
    used |= 1u << bi; ridx[k] = bi;
  }
}

// ---------- fused: r2 row norms (blocks 0..1023) + read/slot scores (blocks 1024..1087) ----------
__global__ __launch_bounds__(256) void k_rs(const float* __restrict__ A, float* __restrict__ r2,
    const float* __restrict__ state, const float* __restrict__ W_rg,
    const float* __restrict__ g_sl, const float* __restrict__ b_sl,
    const float* __restrict__ W_sl, float* __restrict__ rsc, float* __restrict__ ssc) {
  int t = threadIdx.x, l = t & 63, w = t >> 6;
  if (blockIdx.x < 1024) {
    int row = blockIdx.x;
    const float* p = A + (size_t)row * DD;
    float s = 0.f;
    for (int j = t; j < DD; j += 256) { float x = p[j]; s += x * x; }
    s = wred_sum(s);
    __shared__ float sh1[4];
    if (l == 0) sh1[w] = s;
    __syncthreads();
    if (t == 0) r2[row] = sh1[0] + sh1[1] + sh1[2] + sh1[3];
    return;
  }
  int row = blockIdx.x - 1024;
  const float* p = state + (size_t)row * DD;
  float x[4]; float sum = 0.f, sq = 0.f, rs = 0.f;
#pragma unroll
  for (int i = 0; i < 4; i++) {
    int j = t + i * 256;
    x[i] = p[j];
    sum += x[i]; sq += x[i] * x[i];
    rs += x[i] * W_rg[j];
  }
  __shared__ float sh[3][4];
  sum = wred_sum(sum); sq = wred_sum(sq); rs = wred_sum(rs);
  if (l == 0) { sh[0][w] = sum; sh[1][w] = sq; sh[2][w] = rs; }
  __syncthreads();
  float m = (sh[0][0] + sh[0][1] + sh[0][2] + sh[0][3]) * (1.0f / 1024.0f);
  float var = (sh[1][0] + sh[1][1] + sh[1][2] + sh[1][3]) * (1.0f / 1024.0f) - m * m;
  float rsTot = sh[2][0] + sh[2][1] + sh[2][2] + sh[2][3];
  float inv = 1.0f / sqrtf(var + LN_EPS);
  __syncthreads();
  float ss = 0.f;
#pragma unroll
  for (int i = 0; i < 4; i++) {
    int j = t + i * 256;
    float ln = (x[i] - m) * inv * g_sl[j] + b_sl[j];
    ss += ln * W_sl[j];
  }
  ss = wred_sum(ss);
  if (l == 0) sh[0][w] = ss;
  __syncthreads();
  if (t == 0) { rsc[row] = rsTot; ssc[row] = sh[0][0] + sh[0][1] + sh[0][2] + sh[0][3]; }
}

// ---------- fused gate (blocks 0..31) + state update (blocks 32..39) ----------
__global__ __launch_bounds__(256) void k_gs(const float* __restrict__ state,
    const float* __restrict__ rsc, const float* __restrict__ ssc, const float* __restrict__ r2,
    const float* __restrict__ g_moe, const float* __restrict__ b_moe,
    const float* __restrict__ Wg, float* __restrict__ state_ws, float* __restrict__ out) {
  int t = threadIdx.x, l = t & 63, w = t >> 6;
  if (blockIdx.x < 32) {
    // ---- gate part ----
    int b = blockIdx.x >> 2, k = blockIdx.x & 3;
    __shared__ float rs[8];
    __shared__ float red[2][4];
    __shared__ float gl[8];
    if (t < 8) rs[t] = rsc[b * 8 + t];
    __syncthreads();
    int ridx[4]; top4_of8(rs, ridx);
    int s = ridx[k];
    const float* p = state + (size_t)(b * 8 + s) * DD;
    float x[4]; float sum = 0.f, sq = 0.f;
#pragma unroll
    for (int i = 0; i < 4; i++) {
      int j = t + i * 256;
      x[i] = p[j]; sum += x[i]; sq += x[i] * x[i];
    }
    sum = wred_sum(sum); sq = wred_sum(sq);
    if (l == 0) { red[0][w] = sum; red[1][w] = sq; }
    __syncthreads();
    float m = (red[0][0] + red[0][1] + red[0][2] + red[0][3]) * (1.0f / 1024.0f);
    float var = (red[1][0] + red[1][1] + red[1][2] + red[1][3]) * (1.0f / 1024.0f) - m * m;
    float inv = 1.0f / sqrtf(var + LN_EPS);
    float lnv[4];
#pragma unroll
    for (int i = 0; i < 4; i++) {
      int j = t + i * 256;
      lnv[i] = (x[i] - m) * inv * g_moe[j] + b_moe[j];
    }
    __syncthreads();
    for (int e = 0; e < 8; e++) {
      float acc = 0.f;
#pragma unroll
      for (int i = 0; i < 4; i++) acc += lnv[i] * Wg[(size_t)e * DD + t + i * 256];
      acc = wred_sum(acc);
      if (l == 0) red[0][w] = acc;
      __syncthreads();
      if (t == 0) gl[e] = red[0][0] + red[0][1] + red[0][2] + red[0][3];
      __syncthreads();
    }
    if (t == 0) {
      int e0 = 0, e1 = 0; float b0 = -3.4e38f, b1 = -3.4e38f;
      for (int e = 0; e < 8; e++) {
        float v = gl[e];
        if (v > b0) { b1 = b0; e1 = e0; b0 = v; e0 = e; }
        else if (v > b1) { b1 = v; e1 = e; }
      }
      out[O_IDXE + (b * 4 + k) * 2 + 0] = (float)e0;
      out[O_IDXE + (b * 4 + k) * 2 + 1] = (float)e1;
      if (k == 0)
        for (int kk = 0; kk < 4; kk++) out[O_RIDX + b * 4 + kk] = (float)ridx[kk];
    }
    return;
  }
  // ---- state part ----
  int b = blockIdx.x - 32;
  __shared__ float rs2[8];
  if (t < 8) rs2[t] = rsc[b * 8 + t];
  __syncthreads();
  int ridx[4]; top4_of8(rs2, ridx);
  float lr[4];
#pragma unroll
  for (int k = 0; k < 4; k++) lr[k] = ssc[b * 8 + ridx[k]];
  int w0 = 0, w1 = 0; float b0 = -3.4e38f, b1 = -3.4e38f;
#pragma unroll
  for (int k = 0; k < 4; k++) {
    float v = lr[k];
    if (v > b0) { b1 = b0; w1 = w0; b0 = v; w0 = k; }
    else if (v > b1) { b1 = v; w1 = k; }
  }
  int wid0 = ridx[w0], wid1 = ridx[w1];
  float mx = fmaxf(lr[0], lr[1]);
  float e0 = expf(lr[0] - mx), e1 = expf(lr[1] - mx);
  float den = e0 + e1;
  float ws0 = e0 / den, ws1 = e1 / den;
  float resid = 1.0f - (ws0 + ws1);
#pragma unroll
  for (int i = 0; i < 4; i++) {
    int j = t + i * 256;
    float q = 1.0f - 0.03125f * r2[j];  // diag Cayley, c=0.125, O(c^4) dropped
    float lca = 0.f;
#pragma unroll
    for (int k = 0; k < 4; k++)
      lca += tanhf(state[(size_t)(b * 8 + ridx[k]) * DD + j] * q);
    float tj = tanhf(lca * 0.25f);
#pragma unroll
    for (int s = 0; s < 8; s++) {
      float a = (s == wid0) ? ws0 : ((s == wid1) ? ws1 : 0.0f);
      float v = a * tj + resid * state[(size_t)(b * 8 + s) * DD + j];
      state_ws[(size_t)(b * 8 + s) * DD + j] = v;
      out[O_STATE + (size_t)(b * 8 + s) * DD + j] = v;
    }
  }
  if (t == 0) {
    out[O_WIDX + b * 2 + 0] = (float)wid0;
    out[O_WIDX + b * 2 + 1] = (float)wid1;
  }
}

// ---------- MFMA BT GEMM — 64x128 tile, 256 thr / 4 waves, 1024 blocks ----------
// Round-17: granularity experiment. Occupancy has tracked k_gemm perf across 5
// variants (R7 37%/54us best, R11 19%/60us worst); prefetch + LDS economy both
// null. Same 16 waves/CU but 4 independent 4-wave barrier-groups per CU instead
// of 2 8-wave groups: finer interleave of barrier-stall windows. Pipeline
// mechanics identical to round-9 (counted vmcnt(6) = 6 loads/half in flight,
// lgkmcnt-only raw barrier, tied vmcnt(0) drain).
#define MF(CC, AF, BF) CC = __builtin_amdgcn_mfma_f32_16x16x32_bf16(AF, BF, CC, 0, 0, 0)

__device__ __forceinline__ v4f gload4(const float* p) {
  v4f r;
  asm volatile("global_load_dwordx4 %0, %1, off" : "=v"(r) : "v"(p));
  return r;
}

__global__ __launch_bounds__(256, 4) void k_gemm(const float* __restrict__ A,
    const float* __restrict__ Bm, const float* __restrict__ bias, bf16* __restrict__ kvbuf,
    float* __restrict__ lat_last) {
  __shared__ bf16 As_[2][64 * 32];     // A dbuf (4KB each)
  __shared__ bf16 Bs_[2][128 * 32];    // B dbuf (8KB each); epilogue reuses as [64][128]
  const int t = threadIdx.x, l = t & 63, w = t >> 6;   // w: 0..3
  const int lin = blockIdx.y * 8 + blockIdx.x;         // 0..1023
  const int nb = lin >> 7;                             // 0..7
  const int mbp = lin & 127;
  const int mb = ((mbp & 7) << 4) | (mbp >> 3);        // bijective 0..127, XCD-banded
  const int mbase = mb * 64, nbase = nb * 128;
  const int wm = (w >> 1) * 32, wn = (w & 1) * 64;     // wave tile 32x64
  const int lm = l & 15, lk4 = l >> 4;

  v4f c00 = (v4f){0.f,0.f,0.f,0.f}, c01 = (v4f){0.f,0.f,0.f,0.f},
      c02 = (v4f){0.f,0.f,0.f,0.f}, c03 = (v4f){0.f,0.f,0.f,0.f},
      c10 = (v4f){0.f,0.f,0.f,0.f}, c11 = (v4f){0.f,0.f,0.f,0.f},
      c12 = (v4f){0.f,0.f,0.f,0.f}, c13 = (v4f){0.f,0.f,0.f,0.f};

  const int srow = t >> 2;          // 0..63
  const int sch = t & 3;            // k-chunk of 8
  const int swA  = srow * 32 + (sch ^ ((srow >> 1) & 3)) * 8;
  const int swB1 = (srow + 64) * 32 + (sch ^ ((srow >> 1) & 3)) * 8;  // (r+64)>>1 &3 == r>>1 &3
  const int fa_base = (wm + lm) * 32 + ((lk4 ^ ((lm >> 1) & 3)) * 8);
  const int fb_base = (wn + lm) * 32 + ((lk4 ^ ((lm >> 1) & 3)) * 8);

  const float* aRow  = A + (size_t)(mbase + srow) * 1024 + sch * 8;
  const float* bRow0 = Bm + (size_t)(nbase + srow) * 1024 + sch * 8;
  const float* bRow1 = bRow0 + (size_t)64 * 1024;

  // prologue: issue k-chunk 0 (6 loads; in flight until first half1's vmcnt(6))
  v4f a0 = gload4(aRow), a1 = gload4(aRow + 4);
  v4f b00 = gload4(bRow0), b01 = gload4(bRow0 + 4);
  v4f b10 = gload4(bRow1), b11 = gload4(bRow1 + 4);
  v4f na0, na1, nb00, nb01, nb10, nb11;

#define STAGE_AND_MFMA(AV0, AV1, BV00, BV01, BV10, BV11, AB, BB) do { \
    v8bf pa, pb0, pb1; \
    _Pragma("unroll") \
    for (int r = 0; r < 4; r++) { pa[r] = (bf16)AV0[r]; pa[4 + r] = (bf16)AV1[r]; } \
    _Pragma("unroll") \
    for (int r = 0; r < 4; r++) { pb0[r] = (bf16)BV00[r]; pb0[4 + r] = (bf16)BV01[r]; } \
    _Pragma("unroll") \
    for (int r = 0; r < 4; r++) { pb1[r] = (bf16)BV10[r]; pb1[4 + r] = (bf16)BV11[r]; } \
    *(v8bf*)(AB + swA) = pa; \
    *(v8bf*)(BB + swA) = pb0; \
    *(v8bf*)(BB + swB1) = pb1; \
    asm volatile("s_waitcnt lgkmcnt(0)" ::: "memory"); \
    __builtin_amdgcn_s_barrier(); \
    asm volatile("" ::: "memory"); \
    v8bf af0 = *(const v8bf*)(AB + fa_base); \
    v8bf af1 = *(const v8bf*)(AB + fa_base + 512); \
    v8bf bq0 = *(const v8bf*)(BB + fb_base); \
    v8bf bq1 = *(const v8bf*)(BB + fb_base + 512); \
    v8bf bq2 = *(const v8bf*)(BB + fb_base + 1024); \
    v8bf bq3 = *(const v8bf*)(BB + fb_base + 1536); \
    MF(c00, af0, bq0); MF(c01, af0, bq1); MF(c02, af0, bq2); MF(c03, af0, bq3); \
    MF(c10, af1, bq0); MF(c11, af1, bq1); MF(c12, af1, bq2); MF(c13, af1, bq3); \
  } while (0)

  for (int k0 = 0; k0 < 1024; k0 += 64) {
    // ---- half 1: consume cur (chunk k0), prefetch next (chunk k0+32) ----
    {
      const int kn = k0 + 32;
      na0 = gload4(aRow + kn); na1 = gload4(aRow + kn + 4);
      nb00 = gload4(bRow0 + kn); nb01 = gload4(bRow0 + kn + 4);
      nb10 = gload4(bRow1 + kn); nb11 = gload4(bRow1 + kn + 4);
      asm volatile("s_waitcnt vmcnt(6)"
                   : "+v"(a0), "+v"(a1), "+v"(b00), "+v"(b01), "+v"(b10), "+v"(b11));
      STAGE_AND_MFMA(a0, a1, b00, b01, b10, b11, (&As_[0][0]), (&Bs_[0][0]));
    }
    // ---- half 2: consume next (chunk k0+32), prefetch cur (chunk k0+64) ----
    {
      const int kn = (k0 + 64 < 1024) ? (k0 + 64) : k0;  // last: harmless reload
      a0 = gload4(aRow + kn); a1 = gload4(aRow + kn + 4);
      b00 = gload4(bRow0 + kn); b01 = gload4(bRow0 + kn + 4);
      b10 = gload4(bRow1 + kn); b11 = gload4(bRow1 + kn + 4);
      asm volatile("s_waitcnt vmcnt(6)"
                   : "+v"(na0), "+v"(na1), "+v"(nb00), "+v"(nb01), "+v"(nb10), "+v"(nb11));
      STAGE_AND_MFMA(na0, na1, nb00, nb01, nb10, nb11, (&As_[1][0]), (&Bs_[1][0]));
    }
  }
#undef STAGE_AND_MFMA
  // drain the 6 dangling prefetch loads WITH TIES (round-8 lesson).
  asm volatile("s_waitcnt vmcnt(0)"
               : "+v"(a0), "+v"(a1), "+v"(b00), "+v"(b01), "+v"(b10), "+v"(b11));

  // ---- epilogue: 64x128 bf16 tile in Bs_ (16KB = [64][128]), coalesced flush ----
  bf16* ot = &Bs_[0][0];
  const int er = (l >> 4) * 4;
  __syncthreads();                    // all K-loop LDS reads done

#define EPI_ONE(ii, jj, CC) do { \
    _Pragma("unroll") \
    for (int r = 0; r < 4; r++) { \
      int lrow = wm + (ii) * 16 + er + r; \
      int lcol = wn + (jj) * 16 + lm; \
      int grow = mbase + lrow; \
      int col = nbase + lcol; \
      int tok = grow & 1023, bb = grow >> 10; \
      int i2 = col & 511; \
      float fdiv = exp2f((float)i2 * (3.0f / 512.0f)); \
      float aarg = (float)tok / fdiv; \
      float pe = (col < 512) ? sinf(aarg) : cosf(aarg); \
      float v = CC[r] + bias[col] + pe; \
      ot[lrow * 128 + lcol] = (bf16)v; \
      if (tok == 1023) lat_last[(size_t)bb * 1024 + col] = v; \
    } \
  } while (0)

  EPI_ONE(0, 0, c00); EPI_ONE(0, 1, c01); EPI_ONE(0, 2, c02); EPI_ONE(0, 3, c03);
  EPI_ONE(1, 0, c10); EPI_ONE(1, 1, c11); EPI_ONE(1, 2, c12); EPI_ONE(1, 3, c13);
#undef EPI_ONE
  __syncthreads();
  {
    int rr = t >> 2;                  // 0..63
    int cc = (t & 3) * 32;            // 0,32,64,96
    int grow = mbase + rr;
    int tok = grow & 1023, bb = grow >> 10;
    bf16* dst = kvbuf + ((size_t)bb * 1032 + tok) * 1024 + nbase + cc;
    v8bf d0 = *(const v8bf*)(ot + rr * 128 + cc);
    v8bf d1 = *(const v8bf*)(ot + rr * 128 + cc + 8);
    v8bf d2 = *(const v8bf*)(ot + rr * 128 + cc + 16);
    v8bf d3 = *(const v8bf*)(ot + rr * 128 + cc + 24);
    *(v8bf*)dst = d0;
    *(v8bf*)(dst + 8) = d1;
    *(v8bf*)(dst + 16) = d2;
    *(v8bf*)(dst + 24) = d3;
  }
}

// ---------- LN (in-place on kv token rows; state rows from f32; q row from f32 lat_last) ----------
__global__ __launch_bounds__(256) void k_ln(bf16* __restrict__ kvbuf,
    const float* __restrict__ state_ws, const float* __restrict__ gkv, const float* __restrict__ bkv,
    const float* __restrict__ gq, const float* __restrict__ bq,
    float* __restrict__ qln, const float* __restrict__ lat_last) {
  int r = blockIdx.x, t = threadIdx.x, l = t & 63, w = t >> 6;
  int b = r / 1032, p = r % 1032;
  bf16* row = kvbuf + ((size_t)b * 1032 + p) * DD;
  float x[4]; float sum = 0.f, sq = 0.f;
  if (p == 1023) {
    const float* src = lat_last + (size_t)b * DD;
#pragma unroll
    for (int i = 0; i < 4; i++) {
      int j = t + i * 256;
      x[i] = src[j]; sum += x[i]; sq += x[i] * x[i];
    }
  } else if (p < 1024) {
#pragma unroll
    for (int i = 0; i < 4; i++) {
      int j = t + i * 256;
      x[i] = (float)row[j]; sum += x[i]; sq += x[i] * x[i];
    }
  } else {
    const float* src = state_ws + ((size_t)b * 8 + (p - 1024)) * DD;
#pragma unroll
    for (int i = 0; i < 4; i++) {
      int j = t + i * 256;
      x[i] = src[j]; sum += x[i]; sq += x[i] * x[i];
    }
  }
  __shared__ float sh[2][4];
  sum = wred_sum(sum); sq = wred_sum(sq);
  if (l == 0) { sh[0][w] = sum; sh[1][w] = sq; }
  __syncthreads();
  float m = (sh[0][0] + sh[0][1] + sh[0][2] + sh[0][3]) * (1.0f / 1024.0f);
  float var = (sh[1][0] + sh[1][1] + sh[1][2] + sh[1][3]) * (1.0f / 1024.0f) - m * m;
  float inv = 1.0f / sqrtf(var + LN_EPS);
  if (p == 1023) {
#pragma unroll
    for (int i = 0; i < 4; i++) {
      int j = t + i * 256;
      qln[(size_t)b * DD + j] = (x[i] - m) * inv * gq[j] + bq[j];
    }
  }
#pragma unroll
  for (int i = 0; i < 4; i++) {
    int j = t + i * 256;
    row[j] = (bf16)((x[i] - m) * inv * gkv[j] + bkv[j]);
  }
}

// ---------- LN of one f32 row per block (ffn pre-LN) ----------
__global__ __launch_bounds__(256) void k_ln_row(const float* __restrict__ src,
    const float* __restrict__ g, const float* __restrict__ bb, float* __restrict__ dst) {
  int b = blockIdx.x, t = threadIdx.x, l = t & 63, w = t >> 6;
  const float* p = src + (size_t)b * DD;
  float x[4]; float sum = 0.f, sq = 0.f;
#pragma unroll
  for (int i = 0; i < 4; i++) {
    int j = t + i * 256;
    x[i] = p[j]; sum += x[i]; sq += x[i] * x[i];
  }
  __shared__ float sh[2][4];
  sum = wred_sum(sum); sq = wred_sum(sq);
  if (l == 0) { sh[0][w] = sum; sh[1][w] = sq; }
  __syncthreads();
  float m = (sh[0][0] + sh[0][1] + sh[0][2] + sh[0][3]) * (1.0f / 1024.0f);
  float var = (sh[1][0] + sh[1][1] + sh[1][2] + sh[1][3]) * (1.0f / 1024.0f) - m * m;
  float inv = 1.0f / sqrtf(var + LN_EPS);
#pragma unroll
  for (int i = 0; i < 4; i++) {
    int j = t + i * 256;
    dst[(size_t)b * DD + j] = (x[i] - m) * inv * g[j] + bb[j];
  }
}

// ---------- attention pipeline (round-12 per-wave GEMV forms — measured best) ----------
__global__ __launch_bounds__(256) void k_qp(const float* __restrict__ qln,
    const float* __restrict__ Wi, const float* __restrict__ bi, float* __restrict__ qp) {
  int idx = blockIdx.x * 4 + (threadIdx.x >> 6);
  int l = threadIdx.x & 63;
  int b = idx >> 10, n = idx & 1023;
  const float* xr = qln + (size_t)b * DD;
  const float* wr = Wi + (size_t)n * DD;
  float acc = 0.f;
#pragma unroll
  for (int k0 = 0; k0 < 1024; k0 += 64) acc += xr[k0 + l] * wr[k0 + l];
  acc = wred_sum(acc);
  if (l == 0) qp[idx] = acc + bi[n];
}

// ---------- u = q-heads @ Wk^T, 1024-thread (4x d-split); fuses c0 on kt==0 ----------
__global__ __launch_bounds__(1024) void k_u(const float* __restrict__ qp,
    const float* __restrict__ Wi, const float* __restrict__ bi,
    float* __restrict__ u, float* __restrict__ c0) {
  int h = blockIdx.x >> 4, kt = blockIdx.x & 15;
  int t = threadIdx.x;
  __shared__ float qs[8][128];
  __shared__ float red[4][4][2][64];   // [dc][bh][a0/a1][k-lane] 8KB
  {
    int b = t >> 7, d = t & 127;
    qs[b][d] = qp[b * 1024 + h * 128 + d];
  }
  __syncthreads();
  int kl = t & 63;
  int k = kt * 64 + kl;
  int bh = (t >> 6) & 3;
  int dc = t >> 8;                     // 0..3
  const float* wkb = Wi + (size_t)(1024 + h * 128 + dc * 32) * DD + k;
  float a0 = 0.f, a1 = 0.f;
#pragma unroll 8
  for (int d = 0; d < 32; d++) {
    float wv = wkb[(size_t)d * DD];
    a0 += qs[bh][dc * 32 + d] * wv;
    a1 += qs[bh + 4][dc * 32 + d] * wv;
  }
  red[dc][bh][0][kl] = a0;
  red[dc][bh][1][kl] = a1;
  __syncthreads();
  if (dc == 0) {
    float s0 = red[0][bh][0][kl] + red[1][bh][0][kl] + red[2][bh][0][kl] + red[3][bh][0][kl];
    float s1 = red[0][bh][1][kl] + red[1][bh][1][kl] + red[2][bh][1][kl] + red[3][bh][1][kl];
    u[(size_t)(bh * 8 + h) * DD + k] = s0;
    u[(size_t)((bh + 4) * 8 + h) * DD + k] = s1;
  }
  // fused c0 (only 8 blocks do this): c0[b*8+h] = dot128(qp[b,h-slice], bi[1024+h-slice])
  if (kt == 0 && t < 512) {
    int b = t >> 6;
    float a = qp[b * 1024 + h * 128 + kl] * bi[1024 + h * 128 + kl]
            + qp[b * 1024 + h * 128 + 64 + kl] * bi[1024 + h * 128 + 64 + kl];
    a = wred_sum(a);
    if (kl == 0) c0[b * 8 + h] = a;
  }
}

__global__ __launch_bounds__(256) void k_lg(const float* __restrict__ u,
    const bf16* __restrict__ kvbuf, const float* __restrict__ c0, f16* __restrict__ lg) {
  int b = blockIdx.x / 33, tile = blockIdx.x % 33;
  int p0 = tile * 32, t = threadIdx.x;
  __shared__ bf16 kvs[32 * 1032];
  __shared__ float us[8 * 1032];
  const bf16* kvb = kvbuf + (size_t)b * 1032 * DD;
#pragma unroll
  for (int i = 0; i < 16; i++) {
    int flat = (i * 256 + t) * 8;
    int row = flat >> 10, col = flat & 1023;
    int gp = p0 + row; if (gp > 1031) gp = 1031;
    *(v8bf*)(kvs + row * 1032 + col) = *(const v8bf*)(kvb + (size_t)gp * DD + col);
  }
#pragma unroll
  for (int i = 0; i < 8; i++) {
    int flat = (i * 256 + t) * 4;
    int row = flat >> 10, col = flat & 1023;
    *(v4f*)(us + row * 1032 + col) = *(const v4f*)(u + (size_t)(b * 8 + row) * DD + col);
  }
  __syncthreads();
  int pl = t >> 3, h = t & 7;
  if (p0 + pl < 1032) {
    float acc = 0.f;
#pragma unroll
    for (int k = 0; k < 1024; k += 8) {
      v8bf kv8 = *(const v8bf*)(kvs + pl * 1032 + k);
#pragma unroll
      for (int j = 0; j < 8; j++) acc += us[h * 1032 + k + j] * (float)kv8[j];
    }
    lg[(size_t)(b * 8 + h) * 1032 + p0 + pl] =
        (f16)((acc + c0[b * 8 + h]) * 0.08838834764831845f);
  }
}

// ---------- softmax; fuses zeroing of the f32 S buffer (s aliases u, dead after k_lg) ----------
__global__ __launch_bounds__(256) void k_sm(f16* __restrict__ lg, float* __restrict__ s) {
  int t = threadIdx.x, l = t & 63, w = t >> 6;
  // fused s-zero: 65536 floats / 64 blocks = 1024 each (v4f per thread)
  *(v4f*)(s + (size_t)blockIdx.x * 1024 + t * 4) = (v4f){0.f, 0.f, 0.f, 0.f};
  f16* p = lg + (size_t)blockIdx.x * 1032;
  float x[5];
  float mx = -3.4e38f;
#pragma unroll
  for (int i = 0; i < 5; i++) {
    int idx = t + i * 256;
    if (idx < 1032) { x[i] = (float)p[idx]; mx = fmaxf(mx, x[i]); }
  }
  __shared__ float sh[4];
#pragma unroll
  for (int o = 32; o; o >>= 1) mx = fmaxf(mx, __shfl_down(mx, o, 64));
  if (l == 0) sh[w] = mx;
  __syncthreads();
  mx = fmaxf(fmaxf(sh[0], sh[1]), fmaxf(sh[2], sh[3]));
  __syncthreads();
  float sum = 0.f;
#pragma unroll
  for (int i = 0; i < 5; i++) {
    int idx = t + i * 256;
    if (idx < 1032) { x[i] = expf(x[i] - mx); sum += x[i]; }
  }
  sum = wred_sum(sum);
  if (l == 0) sh[w] = sum;
  __syncthreads();
  float inv = 1.0f / (sh[0] + sh[1] + sh[2] + sh[3]);
#pragma unroll
  for (int i = 0; i < 5; i++) {
    int idx = t + i * 256;
    if (idx < 1032) p[idx] = (f16)(x[i] * inv);
  }
}

// ---------- S = P @ KV, p-split for latency hiding ----------
__global__ __launch_bounds__(256) void k_s(const f16* __restrict__ lg,
    const bf16* __restrict__ kvbuf, float* __restrict__ s) {
  int lin = blockIdx.x;              // 8b * 16kt * 8pc
  int b = lin >> 7, kt = (lin >> 3) & 15, pc = lin & 7;
  int t = threadIdx.x, l = t & 63, w = t >> 6;
  __shared__ f16 wl[8][132];         // 129 used
  __shared__ float red[4][8][64];    // 8KB
  for (int i = t; i < 8 * 129; i += 256) {
    int h = i / 129, pp = i % 129;
    wl[h][pp] = lg[(size_t)(b * 8 + h) * 1032 + pc * 129 + pp];
  }
  __syncthreads();
  int k = kt * 64 + l;
  const bf16* kvb = kvbuf + (size_t)b * 1032 * DD + k;
  float a0 = 0.f, a1 = 0.f, a2 = 0.f, a3 = 0.f, a4 = 0.f, a5 = 0.f, a6 = 0.f, a7 = 0.f;
#pragma unroll 4
  for (int pp = w; pp < 129; pp += 4) {
    int p = pc * 129 + pp;
    float kvv = (float)kvb[(size_t)p * DD];
    a0 += (float)wl[0][pp] * kvv;
    a1 += (float)wl[1][pp] * kvv;
    a2 += (float)wl[2][pp] * kvv;
    a3 += (float)wl[3][pp] * kvv;
    a4 += (float)wl[4][pp] * kvv;
    a5 += (float)wl[5][pp] * kvv;
    a6 += (float)wl[6][pp] * kvv;
    a7 += (float)wl[7][pp] * kvv;
  }
  red[w][0][l] = a0; red[w][1][l] = a1; red[w][2][l] = a2; red[w][3][l] = a3;
  red[w][4][l] = a4; red[w][5][l] = a5; red[w][6][l] = a6; red[w][7][l] = a7;
  __syncthreads();
  int hh = t >> 6;                   // 0..3, handles h=hh and h=hh+4
  float r0 = red[0][hh][l] + red[1][hh][l] + red[2][hh][l] + red[3][hh][l];
  float r1 = red[0][hh + 4][l] + red[1][hh + 4][l] + red[2][hh + 4][l] + red[3][hh + 4][l];
  atomicAdd(&s[(size_t)(b * 8 + hh) * DD + k], r0);
  atomicAdd(&s[(size_t)(b * 8 + hh + 4) * DD + k], r1);
}

__global__ __launch_bounds__(256) void k_ov(const float* __restrict__ s,
    const float* __restrict__ Wi, const float* __restrict__ bi, float* __restrict__ o) {
  int idx = blockIdx.x * 4 + (threadIdx.x >> 6);
  int l = threadIdx.x & 63;
  int b = idx >> 10, n = idx & 1023, h = n >> 7;
  const float* sr = s + (size_t)(b * 8 + h) * DD;
  const float* wr = Wi + (size_t)(2048 + n) * DD;
  float acc = 0.f;
#pragma unroll
  for (int k0 = 0; k0 < 1024; k0 += 64) acc += sr[k0 + l] * wr[k0 + l];
  acc = wred_sum(acc);
  if (l == 0) o[idx] = acc + bi[2048 + n];
}

// ---------- tail GEMVs ----------
template <int MODE>
__global__ __launch_bounds__(256) void k_gemv(const float* __restrict__ xin,
    const float* __restrict__ W, const float* __restrict__ bias,
    const float* __restrict__ res, float* __restrict__ outf) {
  int idx = blockIdx.x * 4 + (threadIdx.x >> 6);
  int l = threadIdx.x & 63;
  int b = idx >> 10, n = idx & 1023;
  const float* xr = xin + (size_t)b * DD;
  const float* wr = W + (size_t)n * DD;
  float acc = 0.f;
#pragma unroll
  for (int k0 = 0; k0 < 1024; k0 += 64) acc += xr[k0 + l] * wr[k0 + l];
  acc = wred_sum(acc);
  if (l == 0) {
    float v = acc + bias[n];
    if (MODE == 0) outf[idx] = res[idx] + v;
    if (MODE == 1) outf[idx] = 0.5f * v * (1.0f + erff(v * 0.70710678118654752f));
    if (MODE == 2) outf[idx] = res[idx] + v;
    if (MODE == 3) outf[O_Y + idx] = v;
  }
}

extern "C" void kernel_launch(void* const* d_in, const int* in_sizes, int n_in,
                              void* d_out, int out_size, void* d_ws, size_t ws_size,
                              hipStream_t stream) {
  const float* x        = (const float*)d_in[0];
  const float* state_in = (const float*)d_in[1];
  const float* W_rg     = (const float*)d_in[2];
  const float* ln_moe_g = (const float*)d_in[3];
  const float* ln_moe_b = (const float*)d_in[4];
  const float* W_gate   = (const float*)d_in[5];
  const float* A_skew   = (const float*)d_in[6];
  const float* ln_sl_g  = (const float*)d_in[7];
  const float* ln_sl_b  = (const float*)d_in[8];
  const float* W_slot   = (const float*)d_in[9];
  const float* W_oe     = (const float*)d_in[10];
  const float* b_oe     = (const float*)d_in[11];
  const float* ln_q_g   = (const float*)d_in[12];
  const float* ln_q_b   = (const float*)d_in[13];
  const float* ln_kv_g  = (const float*)d_in[14];
  const float* ln_kv_b  = (const float*)d_in[15];
  const float* in_w     = (const float*)d_in[16];
  const float* in_b     = (const float*)d_in[17];
  const float* out_w    = (const float*)d_in[18];
  const float* out_b    = (const float*)d_in[19];
  const float* ln_f_g   = (const float*)d_in[20];
  const float* ln_f_b   = (const float*)d_in[21];
  const float* W_fc1    = (const float*)d_in[22];
  const float* b_fc1    = (const float*)d_in[23];
  const float* W_fc2    = (const float*)d_in[24];
  const float* b_fc2    = (const float*)d_in[25];
  const float* W_out    = (const float*)d_in[26];
  const float* b_out    = (const float*)d_in[27];

  char* ws = (char*)d_ws;
  bf16*  kvbuf    = (bf16*)(ws + W_KV);
  float* state_ws = (float*)(ws + W_STATE);
  float* u_buf    = (float*)(ws + W_STATE);
  float* s_f32    = (float*)(ws + W_STATE);   // aliases u (dead after k_lg)
  float* lat_last = (float*)(ws + W_LATL);
  float* qln      = (float*)(ws + W_QLN);
  float* c0       = (float*)(ws + W_QLN);     // qln dead after k_qp
  float* r2       = (float*)(ws + W_R2);
  float* rsc      = (float*)(ws + W_RSC);
  float* ssc      = (float*)(ws + W_SSC);
  float* qp       = (float*)(ws + W_OATT);
  f16*   lg       = (f16*)(ws + W_OATT);
  float* o_attn   = (float*)(ws + W_OATT);
  float* lat1     = (float*)(ws + W_LAT1);
  float* lnffn    = (float*)(ws + W_LNFFN);
  float* h1       = (float*)(ws + W_H1);
  float* lat2     = (float*)(ws + W_LAT2);
  float* out = (float*)d_out;

  k_rs<<<1088, 256, 0, stream>>>(A_skew, r2, state_in, W_rg, ln_sl_g, ln_sl_b, W_slot, rsc, ssc);
  k_gs<<<40, 256, 0, stream>>>(state_in, rsc, ssc, r2, ln_moe_g, ln_moe_b, W_gate, state_ws, out);
  k_gemm<<<dim3(8, 128), 256, 0, stream>>>(x, W_oe, b_oe, kvbuf, lat_last);
  k_ln<<<8256, 256, 0, stream>>>(kvbuf, state_ws, ln_kv_g, ln_kv_b, ln_q_g, ln_q_b, qln, lat_last);
  k_qp<<<2048, 256, 0, stream>>>(qln, in_w, in_b, qp);
  k_u<<<128, 1024, 0, stream>>>(qp, in_w, in_b, u_buf, c0);
  k_lg<<<264, 256, 0, stream>>>(u_buf, kvbuf, c0, lg);
  k_sm<<<64, 256, 0, stream>>>(lg, s_f32);
  k_s<<<1024, 256, 0, stream>>>(lg, kvbuf, s_f32);
  k_ov<<<2048, 256, 0, stream>>>(s_f32, in_w, in_b, o_attn);
  k_gemv<0><<<2048, 256, 0, stream>>>(o_attn, out_w, out_b, lat_last, lat1);
  k_ln_row<<<8, 256, 0, stream>>>(lat1, ln_f_g, ln_f_b, lnffn);
  k_gemv<1><<<2048, 256, 0, stream>>>(lnffn, W_fc1, b_fc1, nullptr, h1);
  k_gemv<2><<<2048, 256, 0, stream>>>(h1, W_fc2, b_fc2, lat1, lat2);
  k_gemv<3><<<2048, 256, 0, stream>>>(lat2, W_out, b_out, nullptr, out);
}